// Round 1
// baseline (424.615 us; speedup 1.0000x reference)
//
#include <hip/hip_runtime.h>
#include <hip/hip_bf16.h>

typedef __attribute__((ext_vector_type(8))) short bf16x8;
typedef __attribute__((ext_vector_type(4))) short bf16x4;
typedef __attribute__((ext_vector_type(4))) float f32x4;

#define AS1 __attribute__((address_space(1)))
#define AS3 __attribute__((address_space(3)))

// ---------------------------------------------------------------- LayerNorm
__global__ __launch_bounds__(256)
void ln_kernel(const float* __restrict__ x, const float* __restrict__ g,
               const float* __restrict__ b, __hip_bfloat16* __restrict__ out)
{
    const int row = blockIdx.x;
    const float* xr = x + (size_t)row * 768;
    const int t = threadIdx.x;
    float v0 = xr[t], v1 = xr[t + 256], v2 = xr[t + 512];
    float s = v0 + v1 + v2;
    float ss = v0 * v0 + v1 * v1 + v2 * v2;
#pragma unroll
    for (int off = 1; off < 64; off <<= 1) {
        s  += __shfl_xor(s, off, 64);
        ss += __shfl_xor(ss, off, 64);
    }
    __shared__ float red[8];
    const int wv = t >> 6;
    if ((t & 63) == 0) { red[wv] = s; red[wv + 4] = ss; }
    __syncthreads();
    s  = red[0] + red[1] + red[2] + red[3];
    ss = red[4] + red[5] + red[6] + red[7];
    const float mu = s * (1.0f / 768.0f);
    const float rstd = rsqrtf(ss * (1.0f / 768.0f) - mu * mu + 1e-5f);
    __hip_bfloat16* orow = out + (size_t)row * 768;
    orow[t]       = __float2bfloat16((v0 - mu) * rstd * g[t]       + b[t]);
    orow[t + 256] = __float2bfloat16((v1 - mu) * rstd * g[t + 256] + b[t + 256]);
    orow[t + 512] = __float2bfloat16((v2 - mu) * rstd * g[t + 512] + b[t + 512]);
}

// ------------------------------------------------- weight transpose f32->bf16
// out[c][r] = in[r][c];  in is [R][C] f32, out is [C][R] bf16. R,C multiples of 32.
__global__ __launch_bounds__(256)
void transpose_w(const float* __restrict__ in, __hip_bfloat16* __restrict__ out,
                 int R, int C)
{
    __shared__ float tile[32][33];
    const int c0 = blockIdx.x * 32, r0 = blockIdx.y * 32;
    const int tx = threadIdx.x, ty = threadIdx.y;
#pragma unroll
    for (int i = 0; i < 4; i++)
        tile[ty + i * 8][tx] = in[(size_t)(r0 + ty + i * 8) * C + c0 + tx];
    __syncthreads();
#pragma unroll
    for (int i = 0; i < 4; i++)
        out[(size_t)(c0 + ty + i * 8) * R + r0 + tx] =
            __float2bfloat16(tile[tx][ty + i * 8]);
}

// ---------------------------------------------- QKV weight pack: [H,C,D] f32
// -> out[2304][768] bf16 with out[mat*768 + h*64 + d][c] = w_mat[h][c][d]
__global__ __launch_bounds__(256)
void conv_qkv(const float* __restrict__ wq, const float* __restrict__ wk,
              const float* __restrict__ wv, __hip_bfloat16* __restrict__ out)
{
    const int z = blockIdx.z;
    const int mat = z / 12, h = z % 12;
    const float* w = (mat == 0) ? wq : ((mat == 1) ? wk : wv);
    __shared__ float tile[32][33];
    const int c0 = blockIdx.x * 32;   // c tile: 768/32 = 24
    const int d0 = blockIdx.y * 32;   // d tile: 64/32 = 2
    const int tx = threadIdx.x, ty = threadIdx.y;
#pragma unroll
    for (int i = 0; i < 4; i++)
        tile[ty + i * 8][tx] =
            w[(size_t)h * 768 * 64 + (size_t)(c0 + ty + i * 8) * 64 + d0 + tx];
    __syncthreads();
#pragma unroll
    for (int i = 0; i < 4; i++)
        out[(size_t)(mat * 768 + h * 64 + d0 + ty + i * 8) * 768 + c0 + tx] =
            __float2bfloat16(tile[tx][ty + i * 8]);
}

// ------------------------------------------------------------------- GEMM
// C[M,N] = A[M,K] (bf16 row-major) * Bt[N,K]^T (bf16, stored [N][K]).
// MODE 1: out -> Q/K/V buffers in [B,H,T,D] bf16 (no bias)
// MODE 2: out f32 [M,N] = res + acc + bias
// MODE 3: out bf16 [M,N] = relu(acc + bias)
template<int MODE>
__global__ __launch_bounds__(256)
void gemm_kernel(const __hip_bfloat16* __restrict__ A,
                 const __hip_bfloat16* __restrict__ Bt,
                 const float* __restrict__ bias,
                 const float* __restrict__ res,
                 void* __restrict__ outp,
                 __hip_bfloat16* __restrict__ outK,
                 __hip_bfloat16* __restrict__ outV,
                 int M, int N, int K)
{
    __shared__ alignas(16) __hip_bfloat16 As[128 * 32];
    __shared__ alignas(16) __hip_bfloat16 Bs[128 * 32];
    const int tid = threadIdx.x;
    const int wave = tid >> 6, lane = tid & 63;
    const int m0 = blockIdx.y * 128, n0 = blockIdx.x * 128;
    const int wm = (wave >> 1) * 64, wn = (wave & 1) * 64;
    f32x4 acc[4][4] = {};

    const int srow = lane >> 2;          // row within 16-row chunk
    const int scol = (lane & 3) * 16;    // byte col within 64B row

    for (int k0 = 0; k0 < K; k0 += 32) {
        __syncthreads();
#pragma unroll
        for (int c = 0; c < 2; ++c) {
            const int ch = wave + c * 4;
            const int row = ch * 16 + srow;
            const char* ga = (const char*)A  + ((size_t)(m0 + row) * K + k0) * 2 + scol;
            const char* gb = (const char*)Bt + ((size_t)(n0 + row) * K + k0) * 2 + scol;
            __builtin_amdgcn_global_load_lds((const AS1 void*)ga,
                (AS3 void*)((char*)As + ch * 1024), 16, 0, 0);
            __builtin_amdgcn_global_load_lds((const AS1 void*)gb,
                (AS3 void*)((char*)Bs + ch * 1024), 16, 0, 0);
        }
        __syncthreads();
        const int fr = lane & 15, fg = lane >> 4;
        bf16x8 af[4], bfr[4];
#pragma unroll
        for (int i = 0; i < 4; i++)
            af[i] = *(const bf16x8*)&As[(wm + i * 16 + fr) * 32 + fg * 8];
#pragma unroll
        for (int j = 0; j < 4; j++)
            bfr[j] = *(const bf16x8*)&Bs[(wn + j * 16 + fr) * 32 + fg * 8];
#pragma unroll
        for (int i = 0; i < 4; i++)
#pragma unroll
            for (int j = 0; j < 4; j++)
                acc[i][j] = __builtin_amdgcn_mfma_f32_16x16x32_bf16(
                    af[i], bfr[j], acc[i][j], 0, 0, 0);
    }

    const int fr = lane & 15, fg = lane >> 4;
#pragma unroll
    for (int j = 0; j < 4; j++) {
        const int n = n0 + wn + j * 16 + fr;
        const float bv = (MODE == 2 || MODE == 3) ? bias[n] : 0.0f;
#pragma unroll
        for (int i = 0; i < 4; i++) {
#pragma unroll
            for (int r = 0; r < 4; r++) {
                const int m = m0 + wm + i * 16 + fg * 4 + r;
                float v = acc[i][j][r] + bv;
                if (MODE == 3) v = fmaxf(v, 0.0f);
                if (MODE == 2) {
                    ((float*)outp)[(size_t)m * N + n] = res[(size_t)m * N + n] + v;
                } else if (MODE == 1) {
                    __hip_bfloat16* dst; int nc;
                    if (n < 768)       { dst = (__hip_bfloat16*)outp; nc = n; }
                    else if (n < 1536) { dst = outK; nc = n - 768; }
                    else               { dst = outV; nc = n - 1536; }
                    const int hh = nc >> 6, dd = nc & 63;
                    const int bidx = m >> 11, tt = m & 2047;
                    dst[(((size_t)bidx * 12 + hh) * 2048 + tt) * 64 + dd] =
                        __float2bfloat16(v);
                } else {
                    ((__hip_bfloat16*)outp)[(size_t)m * N + n] = __float2bfloat16(v);
                }
            }
        }
    }
}

// ----------------------------------------------------------- causal attention
// Q,K,V: [B*H, 2048, 64] bf16.  out: [B*2048, 768] bf16 (head-concat layout).
// Per block: one (b,h), 64 queries; 4 waves x 16 queries.
// S^T = K*Q^T via mfma 16x16x32 (softmax stats lane-uniform: q = lane&15);
// O^T = V^T*P^T via mfma 16x16x16 (B-operand layout == S^T D-layout, no shuffle).
__global__ __launch_bounds__(256)
void attn_kernel(const __hip_bfloat16* __restrict__ Q,
                 const __hip_bfloat16* __restrict__ Kg,
                 const __hip_bfloat16* __restrict__ Vg,
                 __hip_bfloat16* __restrict__ out)
{
    __shared__ alignas(16) __hip_bfloat16 Ks[16 * 64];   // XOR-swizzled
    __shared__ alignas(16) __hip_bfloat16 Vt[64 * 20];   // V^T, stride 20 (40B)
    const int tid = threadIdx.x, wave = tid >> 6, lane = tid & 63;
    const int bh = blockIdx.y;
    const int q0 = blockIdx.x * 64;
    const int b = bh / 12, h = bh % 12;
    const __hip_bfloat16* qb = Q  + (size_t)bh * 2048 * 64;
    const __hip_bfloat16* kb = Kg + (size_t)bh * 2048 * 64;
    const __hip_bfloat16* vb = Vg + (size_t)bh * 2048 * 64;
    const int fr = lane & 15, fg = lane >> 4;
    const int q = q0 + wave * 16 + fr;      // this lane's query row
    const bf16x8 qf0 = *(const bf16x8*)(qb + (size_t)q * 64 + fg * 8);
    const bf16x8 qf1 = *(const bf16x8*)(qb + (size_t)q * 64 + 32 + fg * 8);
    f32x4 o0 = {}, o1 = {}, o2 = {}, o3 = {};   // O^T: d rows 0..63, col q
    float mrun = -1e30f, lrun = 0.0f;
    const int qmax = q0 + wave * 16 + 15;
    const int NT = q0 / 16 + 4;
    const int vkv = tid >> 4, vd0 = (tid & 15) * 4;   // V^T staging indices

    for (int t = 0; t < NT; ++t) {
        const int kv0 = t * 16;
        __syncthreads();
        if (wave < 2) {  // stage K tile [16][64] with XOR-swizzled source
            const int L = wave * 1024 + lane * 16;
            const int krow = L >> 7, kcol = L & 127;
            const char* gk = (const char*)kb + (size_t)(kv0 + krow) * 128 +
                             (kcol ^ ((krow & 7) << 4));
            __builtin_amdgcn_global_load_lds((const AS1 void*)gk,
                (AS3 void*)((char*)Ks + wave * 1024), 16, 0, 0);
        }
        {   // stage V^T (reg-staged transpose)
            bf16x4 vv = *(const bf16x4*)(vb + (size_t)(kv0 + vkv) * 64 + vd0);
#pragma unroll
            for (int jj = 0; jj < 4; jj++)
                Vt[(vd0 + jj) * 20 + vkv] = ((const __hip_bfloat16*)&vv)[jj];
        }
        __syncthreads();
        if (kv0 > qmax) continue;   // wave-uniform; barrier count still matches

        // ---- S^T = K * Q^T
        f32x4 s4 = {};
        {
            const bf16x8 kf0 = *(const bf16x8*)((const char*)Ks + fr * 128 +
                                ((fg * 16)      ^ ((fr & 7) << 4)));
            const bf16x8 kf1 = *(const bf16x8*)((const char*)Ks + fr * 128 +
                                ((64 + fg * 16) ^ ((fr & 7) << 4)));
            s4 = __builtin_amdgcn_mfma_f32_16x16x32_bf16(kf0, qf0, s4, 0, 0, 0);
            s4 = __builtin_amdgcn_mfma_f32_16x16x32_bf16(kf1, qf1, s4, 0, 0, 0);
        }
        // ---- masked online softmax (stats per q = lane&15, uniform per lane)
        float sc[4];
#pragma unroll
        for (int r = 0; r < 4; r++) {
            const int kv = kv0 + fg * 4 + r;
            sc[r] = (kv <= q) ? s4[r] * 0.125f : -1e30f;
        }
        float tm = fmaxf(fmaxf(sc[0], sc[1]), fmaxf(sc[2], sc[3]));
        tm = fmaxf(tm, __shfl_xor(tm, 16, 64));
        tm = fmaxf(tm, __shfl_xor(tm, 32, 64));
        const float mnew = fmaxf(mrun, tm);
        const float alpha = __expf(mrun - mnew);
        const float p0 = __expf(sc[0] - mnew), p1 = __expf(sc[1] - mnew);
        const float p2 = __expf(sc[2] - mnew), p3 = __expf(sc[3] - mnew);
        float ps = p0 + p1 + p2 + p3;
        ps += __shfl_xor(ps, 16, 64);
        ps += __shfl_xor(ps, 32, 64);
        lrun = lrun * alpha + ps;
        mrun = mnew;
        bf16x4 pf;
        {
            __hip_bfloat16* pp = (__hip_bfloat16*)&pf;
            pp[0] = __float2bfloat16(p0); pp[1] = __float2bfloat16(p1);
            pp[2] = __float2bfloat16(p2); pp[3] = __float2bfloat16(p3);
        }
#pragma unroll
        for (int e = 0; e < 4; e++) {
            o0[e] *= alpha; o1[e] *= alpha; o2[e] *= alpha; o3[e] *= alpha;
        }
        // ---- O^T += V^T * P^T  (A = V^T rows d, B = P^T; K=16)
        o0 = __builtin_amdgcn_mfma_f32_16x16x16bf16_1k(
            *(const bf16x4*)&Vt[( 0 + fr) * 20 + fg * 4], pf, o0, 0, 0, 0);
        o1 = __builtin_amdgcn_mfma_f32_16x16x16bf16_1k(
            *(const bf16x4*)&Vt[(16 + fr) * 20 + fg * 4], pf, o1, 0, 0, 0);
        o2 = __builtin_amdgcn_mfma_f32_16x16x16bf16_1k(
            *(const bf16x4*)&Vt[(32 + fr) * 20 + fg * 4], pf, o2, 0, 0, 0);
        o3 = __builtin_amdgcn_mfma_f32_16x16x16bf16_1k(
            *(const bf16x4*)&Vt[(48 + fr) * 20 + fg * 4], pf, o3, 0, 0, 0);
    }

    const float inv = 1.0f / lrun;
    __hip_bfloat16* ob = out + ((size_t)b * 2048 + q) * 768 + h * 64;
#pragma unroll
    for (int r = 0; r < 4; r++) {
        ob[ 0 + fg * 4 + r] = __float2bfloat16(o0[r] * inv);
        ob[16 + fg * 4 + r] = __float2bfloat16(o1[r] * inv);
        ob[32 + fg * 4 + r] = __float2bfloat16(o2[r] * inv);
        ob[48 + fg * 4 + r] = __float2bfloat16(o3[r] * inv);
    }
}

// ---------------------------------------------------------------------------
extern "C" void kernel_launch(void* const* d_in, const int* in_sizes, int n_in,
                              void* d_out, int out_size, void* d_ws, size_t ws_size,
                              hipStream_t stream)
{
    const float* x      = (const float*)d_in[0];
    const float* wq     = (const float*)d_in[1];
    const float* wk     = (const float*)d_in[2];
    const float* wv     = (const float*)d_in[3];
    const float* w_proj = (const float*)d_in[4];
    const float* b_proj = (const float*)d_in[5];
    const float* w1     = (const float*)d_in[6];
    const float* b1     = (const float*)d_in[7];
    const float* w2     = (const float*)d_in[8];
    const float* b2     = (const float*)d_in[9];
    const float* ln1_g  = (const float*)d_in[10];
    const float* ln1_b  = (const float*)d_in[11];
    const float* ln2_g  = (const float*)d_in[12];
    const float* ln2_b  = (const float*)d_in[13];
    float* out = (float*)d_out;

    char* w = (char*)d_ws;
    size_t off = 0;
    auto alloc = [&](size_t bytes) {
        void* p = w + off;
        off += (bytes + 255) & ~(size_t)255;
        return p;
    };
    __hip_bfloat16* h_ln    = (__hip_bfloat16*)alloc(8192ull * 768 * 2);
    __hip_bfloat16* wt_qkv  = (__hip_bfloat16*)alloc(2304ull * 768 * 2);
    __hip_bfloat16* wt_proj = (__hip_bfloat16*)alloc(768ull * 768 * 2);
    __hip_bfloat16* wt1     = (__hip_bfloat16*)alloc(3072ull * 768 * 2);
    __hip_bfloat16* wt2     = (__hip_bfloat16*)alloc(768ull * 3072 * 2);
    __hip_bfloat16* qbuf    = (__hip_bfloat16*)alloc(8192ull * 768 * 2);
    __hip_bfloat16* kbuf    = (__hip_bfloat16*)alloc(8192ull * 768 * 2);
    __hip_bfloat16* vbuf    = (__hip_bfloat16*)alloc(8192ull * 768 * 2);
    __hip_bfloat16* attn_o  = (__hip_bfloat16*)alloc(8192ull * 768 * 2);
    float*          x1      = (float*)alloc(8192ull * 768 * 4);
    __hip_bfloat16* h2      = (__hip_bfloat16*)alloc(8192ull * 768 * 2);
    __hip_bfloat16* a1      = qbuf;  // alias: q/k/v/attn_o (50.3MB) dead by FFN1

    // weight preprocessing (every call: no static caching allowed)
    conv_qkv<<<dim3(24, 2, 36), dim3(32, 8), 0, stream>>>(wq, wk, wv, wt_qkv);
    transpose_w<<<dim3(24, 24), dim3(32, 8), 0, stream>>>(w_proj, wt_proj, 768, 768);
    transpose_w<<<dim3(96, 24), dim3(32, 8), 0, stream>>>(w1, wt1, 768, 3072);
    transpose_w<<<dim3(24, 96), dim3(32, 8), 0, stream>>>(w2, wt2, 3072, 768);

    // attention sublayer
    ln_kernel<<<8192, 256, 0, stream>>>(x, ln1_g, ln1_b, h_ln);
    gemm_kernel<1><<<dim3(18, 64), 256, 0, stream>>>(
        h_ln, wt_qkv, nullptr, nullptr, qbuf, kbuf, vbuf, 8192, 2304, 768);
    attn_kernel<<<dim3(32, 48), 256, 0, stream>>>(qbuf, kbuf, vbuf, attn_o);
    gemm_kernel<2><<<dim3(6, 64), 256, 0, stream>>>(
        attn_o, wt_proj, b_proj, x, x1, nullptr, nullptr, 8192, 768, 768);

    // FFN sublayer
    ln_kernel<<<8192, 256, 0, stream>>>(x1, ln2_g, ln2_b, h2);
    gemm_kernel<3><<<dim3(24, 64), 256, 0, stream>>>(
        h2, wt1, b1, nullptr, a1, nullptr, nullptr, 8192, 3072, 768);
    gemm_kernel<2><<<dim3(6, 64), 256, 0, stream>>>(
        a1, wt2, b2, x1, out, nullptr, nullptr, 8192, 768, 3072);
}

// Round 3
// 392.517 us; speedup vs baseline: 1.0818x; 1.0818x over previous
//
#include <hip/hip_runtime.h>
#include <hip/hip_bf16.h>

typedef __attribute__((ext_vector_type(8))) short bf16x8;
typedef __attribute__((ext_vector_type(4))) short bf16x4;
typedef __attribute__((ext_vector_type(4))) float f32x4;

#define AS1 __attribute__((address_space(1)))
#define AS3 __attribute__((address_space(3)))

// ---------------------------------------------------------------- LayerNorm
__global__ __launch_bounds__(256)
void ln_kernel(const float* __restrict__ x, const float* __restrict__ g,
               const float* __restrict__ b, __hip_bfloat16* __restrict__ out)
{
    const int row = blockIdx.x;
    const float* xr = x + (size_t)row * 768;
    const int t = threadIdx.x;
    float v0 = xr[t], v1 = xr[t + 256], v2 = xr[t + 512];
    float s = v0 + v1 + v2;
    float ss = v0 * v0 + v1 * v1 + v2 * v2;
#pragma unroll
    for (int off = 1; off < 64; off <<= 1) {
        s  += __shfl_xor(s, off, 64);
        ss += __shfl_xor(ss, off, 64);
    }
    __shared__ float red[8];
    const int wv = t >> 6;
    if ((t & 63) == 0) { red[wv] = s; red[wv + 4] = ss; }
    __syncthreads();
    s  = red[0] + red[1] + red[2] + red[3];
    ss = red[4] + red[5] + red[6] + red[7];
    const float mu = s * (1.0f / 768.0f);
    const float rstd = rsqrtf(ss * (1.0f / 768.0f) - mu * mu + 1e-5f);
    __hip_bfloat16* orow = out + (size_t)row * 768;
    orow[t]       = __float2bfloat16((v0 - mu) * rstd * g[t]       + b[t]);
    orow[t + 256] = __float2bfloat16((v1 - mu) * rstd * g[t + 256] + b[t + 256]);
    orow[t + 512] = __float2bfloat16((v2 - mu) * rstd * g[t + 512] + b[t + 512]);
}

// ------------------------------------------------- weight transpose f32->bf16
__global__ __launch_bounds__(256)
void transpose_w(const float* __restrict__ in, __hip_bfloat16* __restrict__ out,
                 int R, int C)
{
    __shared__ float tile[32][33];
    const int c0 = blockIdx.x * 32, r0 = blockIdx.y * 32;
    const int tx = threadIdx.x, ty = threadIdx.y;
#pragma unroll
    for (int i = 0; i < 4; i++)
        tile[ty + i * 8][tx] = in[(size_t)(r0 + ty + i * 8) * C + c0 + tx];
    __syncthreads();
#pragma unroll
    for (int i = 0; i < 4; i++)
        out[(size_t)(c0 + ty + i * 8) * R + r0 + tx] =
            __float2bfloat16(tile[tx][ty + i * 8]);
}

// ---------------------------------------------- QKV weight pack: [H,C,D] f32
__global__ __launch_bounds__(256)
void conv_qkv(const float* __restrict__ wq, const float* __restrict__ wk,
              const float* __restrict__ wv, __hip_bfloat16* __restrict__ out)
{
    const int z = blockIdx.z;
    const int mat = z / 12, h = z % 12;
    const float* w = (mat == 0) ? wq : ((mat == 1) ? wk : wv);
    __shared__ float tile[32][33];
    const int c0 = blockIdx.x * 32;
    const int d0 = blockIdx.y * 32;
    const int tx = threadIdx.x, ty = threadIdx.y;
#pragma unroll
    for (int i = 0; i < 4; i++)
        tile[ty + i * 8][tx] =
            w[(size_t)h * 768 * 64 + (size_t)(c0 + ty + i * 8) * 64 + d0 + tx];
    __syncthreads();
#pragma unroll
    for (int i = 0; i < 4; i++)
        out[(size_t)(mat * 768 + h * 64 + d0 + ty + i * 8) * 768 + c0 + tx] =
            __float2bfloat16(tile[tx][ty + i * 8]);
}

// ------------------------------------------------------------------- GEMM
// C[M,N] = A[M,K] (bf16 row-major) * Bt[N,K]^T.
// MODE 1: out -> Q [bh][t][d] (prescaled 0.125*log2e), K [bh][t][d],
//         V TRANSPOSED [bh][d][t] (bf16x4 stores along t)
// MODE 2: out f32 [M,N] = res + acc + bias
// MODE 3: out bf16 [M,N] = relu(acc + bias)
template<int MODE>
__global__ __launch_bounds__(256)
void gemm_kernel(const __hip_bfloat16* __restrict__ A,
                 const __hip_bfloat16* __restrict__ Bt,
                 const float* __restrict__ bias,
                 const float* __restrict__ res,
                 void* __restrict__ outp,
                 __hip_bfloat16* __restrict__ outK,
                 __hip_bfloat16* __restrict__ outV,
                 int M, int N, int K)
{
    __shared__ alignas(16) __hip_bfloat16 As[128 * 32];
    __shared__ alignas(16) __hip_bfloat16 Bs[128 * 32];
    const int tid = threadIdx.x;
    const int wave = tid >> 6, lane = tid & 63;
    const int m0 = blockIdx.y * 128, n0 = blockIdx.x * 128;
    const int wm = (wave >> 1) * 64, wn = (wave & 1) * 64;
    f32x4 acc[4][4] = {};

    const int srow = lane >> 2;
    const int scol = (lane & 3) * 16;

    for (int k0 = 0; k0 < K; k0 += 32) {
        __syncthreads();
#pragma unroll
        for (int c = 0; c < 2; ++c) {
            const int ch = wave + c * 4;
            const int row = ch * 16 + srow;
            const char* ga = (const char*)A  + ((size_t)(m0 + row) * K + k0) * 2 + scol;
            const char* gb = (const char*)Bt + ((size_t)(n0 + row) * K + k0) * 2 + scol;
            __builtin_amdgcn_global_load_lds((const AS1 void*)ga,
                (AS3 void*)((char*)As + ch * 1024), 16, 0, 0);
            __builtin_amdgcn_global_load_lds((const AS1 void*)gb,
                (AS3 void*)((char*)Bs + ch * 1024), 16, 0, 0);
        }
        __syncthreads();
        const int fr = lane & 15, fg = lane >> 4;
        bf16x8 af[4], bfr[4];
#pragma unroll
        for (int i = 0; i < 4; i++)
            af[i] = *(const bf16x8*)&As[(wm + i * 16 + fr) * 32 + fg * 8];
#pragma unroll
        for (int j = 0; j < 4; j++)
            bfr[j] = *(const bf16x8*)&Bs[(wn + j * 16 + fr) * 32 + fg * 8];
#pragma unroll
        for (int i = 0; i < 4; i++)
#pragma unroll
            for (int j = 0; j < 4; j++)
                acc[i][j] = __builtin_amdgcn_mfma_f32_16x16x32_bf16(
                    af[i], bfr[j], acc[i][j], 0, 0, 0);
    }

    const int fr = lane & 15, fg = lane >> 4;
#pragma unroll
    for (int j = 0; j < 4; j++) {
        const int n = n0 + wn + j * 16 + fr;
        if (MODE == 1 && n >= 1536) {
            // V transposed: vbuf[bh][d][t], vector store along t
            const int hh = (n - 1536) >> 6, dd = (n - 1536) & 63;
#pragma unroll
            for (int i = 0; i < 4; i++) {
                const int m = m0 + wm + i * 16 + fg * 4;
                const int bidx = m >> 11, tt = m & 2047;
                bf16x4 pk;
                __hip_bfloat16* pp = (__hip_bfloat16*)&pk;
#pragma unroll
                for (int r = 0; r < 4; r++)
                    pp[r] = __float2bfloat16(acc[i][j][r]);
                *(bf16x4*)&outV[(((size_t)bidx * 12 + hh) * 64 + dd) * 2048 + tt] = pk;
            }
            continue;
        }
        const float bv = (MODE == 2 || MODE == 3) ? bias[n] : 0.0f;
#pragma unroll
        for (int i = 0; i < 4; i++) {
#pragma unroll
            for (int r = 0; r < 4; r++) {
                const int m = m0 + wm + i * 16 + fg * 4 + r;
                float v = acc[i][j][r] + bv;
                if (MODE == 3) v = fmaxf(v, 0.0f);
                if (MODE == 2) {
                    ((float*)outp)[(size_t)m * N + n] = res[(size_t)m * N + n] + v;
                } else if (MODE == 1) {
                    __hip_bfloat16* dst; int nc;
                    if (n < 768) { dst = (__hip_bfloat16*)outp; nc = n;
                                   v *= 0.18033688011112042f; /* 0.125*log2e */ }
                    else         { dst = outK; nc = n - 768; }
                    const int hh = nc >> 6, dd = nc & 63;
                    const int bidx = m >> 11, tt = m & 2047;
                    dst[(((size_t)bidx * 12 + hh) * 2048 + tt) * 64 + dd] =
                        __float2bfloat16(v);
                } else {
                    ((__hip_bfloat16*)outp)[(size_t)m * N + n] = __float2bfloat16(v);
                }
            }
        }
    }
}

// ----------------------------------------------------------- causal attention
// Q,K: [B*H, 2048, 64] bf16 (Q prescaled by 0.125*log2e). V: [B*H, 64, 2048]
// bf16 (pre-transposed by QKV GEMM). out: [B*2048, 768] bf16.
// Per block: one (b,h), 128 queries; 4 waves x 32 q. KVBLK=64, double-buffered.
// K tile [64 kv][64 d] and V^T tile [64 d][64 kv] both XOR-swizzled in LDS
// (linear global_load_lds dest + inverse-swizzled global source, rule #21).
// S^T = K*Q^T (16x16x32); O^T += V^T*P^T (16x16x16, B-op == S^T layout).
__global__ __launch_bounds__(256)
void attn_kernel(const __hip_bfloat16* __restrict__ Q,
                 const __hip_bfloat16* __restrict__ Kg,
                 const __hip_bfloat16* __restrict__ Vg,
                 __hip_bfloat16* __restrict__ out)
{
    __shared__ alignas(16) char lds[32768];   // [cur][ K 8KB | V^T 8KB ]
    const int tid = threadIdx.x, wave = tid >> 6, lane = tid & 63;
    const int fr = lane & 15, fg = lane >> 4;
    const int bh = blockIdx.y, bx = blockIdx.x;
    const int q0 = bx * 128;
    const int b = bh / 12, h = bh % 12;
    const __hip_bfloat16* qb = Q  + (size_t)bh * 2048 * 64;
    const __hip_bfloat16* kb = Kg + (size_t)bh * 2048 * 64;
    const __hip_bfloat16* vb = Vg + (size_t)bh * 2048 * 64;   // [64 d][2048 t]
    const int q0w = q0 + wave * 32;

    bf16x8 qfrag[2][2];
#pragma unroll
    for (int qf = 0; qf < 2; qf++)
#pragma unroll
        for (int hh = 0; hh < 2; hh++)
            qfrag[qf][hh] = *(const bf16x8*)(qb +
                (size_t)(q0w + qf * 16 + fr) * 64 + hh * 32 + fg * 8);

    f32x4 o[2][4] = {};
    float mrun[2] = {-1e30f, -1e30f}, lrun[2] = {0.f, 0.f};

    // staging: chunk n = wave*64+lane+256r covers LDS bytes n*16..+16 (linear)
    int ksoff[2], vsoff[2];
#pragma unroll
    for (int r = 0; r < 2; r++) {
        const int n = wave * 64 + lane + 256 * r;
        const int row = n >> 3;                       // tile row 0..63
        const int swz = (((n & 7) << 4)) ^ ((row & 7) << 4);
        ksoff[r] = row * 128  + swz;                  // K rows: 128B global stride
        vsoff[r] = row * 4096 + swz;                  // V^T rows: 4096B global stride
    }

    auto STAGE = [&](int cur, int kv0) {
        const char* kx = (const char*)kb + (size_t)kv0 * 128;
        const char* vx = (const char*)vb + (size_t)kv0 * 2;
#pragma unroll
        for (int r = 0; r < 2; r++) {
            __builtin_amdgcn_global_load_lds((const AS1 void*)(kx + ksoff[r]),
                (AS3 void*)(lds + cur * 16384 + r * 4096 + wave * 1024), 16, 0, 0);
            __builtin_amdgcn_global_load_lds((const AS1 void*)(vx + vsoff[r]),
                (AS3 void*)(lds + cur * 16384 + 8192 + r * 4096 + wave * 1024), 16, 0, 0);
        }
    };

    const int NT = bx * 2 + 2;
    STAGE(0, 0);
    __syncthreads();
    int cur = 0;

    for (int t = 0; t < NT; ++t) {
        if (t + 1 < NT) STAGE(cur ^ 1, (t + 1) << 6);
        const int kv0 = t << 6;
        if (kv0 <= q0w + 31) {          // wave-uniform
            const char* Kb = lds + cur * 16384;
            const char* Vb = Kb + 8192;
            bf16x8 kf[4][2];
#pragma unroll
            for (int c = 0; c < 4; c++)
#pragma unroll
                for (int hh = 0; hh < 2; hh++)
                    kf[c][hh] = *(const bf16x8*)(Kb + (16 * c + fr) * 128 +
                                ((hh * 64 + fg * 16) ^ ((fr & 7) << 4)));
            bf16x4 pf[2][4];
#pragma unroll
            for (int qf = 0; qf < 2; qf++) {
                const int qlo = q0w + qf * 16;
                f32x4 s[4];
                __builtin_amdgcn_s_setprio(1);
#pragma unroll
                for (int c = 0; c < 4; c++) {
                    f32x4 z = {};
                    s[c] = __builtin_amdgcn_mfma_f32_16x16x32_bf16(
                        kf[c][0], qfrag[qf][0], z, 0, 0, 0);
                    s[c] = __builtin_amdgcn_mfma_f32_16x16x32_bf16(
                        kf[c][1], qfrag[qf][1], s[c], 0, 0, 0);
                }
                __builtin_amdgcn_s_setprio(0);
                if (kv0 + 63 > qlo) {   // partial-diagonal tile only
                    const int qv = qlo + fr;
#pragma unroll
                    for (int c = 0; c < 4; c++)
#pragma unroll
                        for (int r = 0; r < 4; r++)
                            if (kv0 + 16 * c + 4 * fg + r > qv) s[c][r] = -1e30f;
                }
                float tm = -1e30f;
#pragma unroll
                for (int c = 0; c < 4; c++)
                    tm = fmaxf(tm, fmaxf(fmaxf(s[c][0], s[c][1]),
                                         fmaxf(s[c][2], s[c][3])));
                tm = fmaxf(tm, __shfl_xor(tm, 16, 64));
                tm = fmaxf(tm, __shfl_xor(tm, 32, 64));
                float mr = mrun[qf];
                if (!__all(tm <= mr + 8.f)) {      // defer-max (T13)
                    const float mnew = fmaxf(mr, tm);
                    const float al = exp2f(mr - mnew);
                    lrun[qf] *= al;
#pragma unroll
                    for (int i = 0; i < 4; i++)
#pragma unroll
                        for (int e = 0; e < 4; e++) o[qf][i][e] *= al;
                    mrun[qf] = mnew; mr = mnew;
                }
                float ps = 0.f;
#pragma unroll
                for (int c = 0; c < 4; c++) {
                    const float p0 = exp2f(s[c][0] - mr), p1 = exp2f(s[c][1] - mr);
                    const float p2 = exp2f(s[c][2] - mr), p3 = exp2f(s[c][3] - mr);
                    ps += (p0 + p1) + (p2 + p3);
                    __hip_bfloat16* pp = (__hip_bfloat16*)&pf[qf][c];
                    pp[0] = __float2bfloat16(p0); pp[1] = __float2bfloat16(p1);
                    pp[2] = __float2bfloat16(p2); pp[3] = __float2bfloat16(p3);
                }
                ps += __shfl_xor(ps, 16, 64);
                ps += __shfl_xor(ps, 32, 64);
                lrun[qf] += ps;
            }
            // ---- PV: O^T += V^T * P^T  (A = V^T swizzled ds_read_b64)
            bf16x4 vf[4][4];
#pragma unroll
            for (int i = 0; i < 4; i++)
#pragma unroll
                for (int c = 0; c < 4; c++)
                    vf[i][c] = *(const bf16x4*)(Vb + (16 * i + fr) * 128 +
                                ((32 * c + 8 * fg) ^ ((fr & 7) << 4)));
            __builtin_amdgcn_s_setprio(1);
#pragma unroll
            for (int i = 0; i < 4; i++)
#pragma unroll
                for (int qf = 0; qf < 2; qf++)
#pragma unroll
                    for (int c = 0; c < 4; c++)
                        o[qf][i] = __builtin_amdgcn_mfma_f32_16x16x16bf16_1k(
                            vf[i][c], pf[qf][c], o[qf][i], 0, 0, 0);
            __builtin_amdgcn_s_setprio(0);
        }
        __syncthreads();
        cur ^= 1;
    }

#pragma unroll
    for (int qf = 0; qf < 2; qf++) {
        const float inv = 1.0f / lrun[qf];
        __hip_bfloat16* ob = out +
            ((size_t)(b * 2048 + q0w + qf * 16 + fr)) * 768 + h * 64;
#pragma unroll
        for (int i = 0; i < 4; i++) {
            bf16x4 pk;
            __hip_bfloat16* pp = (__hip_bfloat16*)&pk;
#pragma unroll
            for (int r = 0; r < 4; r++)
                pp[r] = __float2bfloat16(o[qf][i][r] * inv);
            *(bf16x4*)(ob + 16 * i + 4 * fg) = pk;
        }
    }
}

// ---------------------------------------------------------------------------
extern "C" void kernel_launch(void* const* d_in, const int* in_sizes, int n_in,
                              void* d_out, int out_size, void* d_ws, size_t ws_size,
                              hipStream_t stream)
{
    const float* x      = (const float*)d_in[0];
    const float* wq     = (const float*)d_in[1];
    const float* wk     = (const float*)d_in[2];
    const float* wv     = (const float*)d_in[3];
    const float* w_proj = (const float*)d_in[4];
    const float* b_proj = (const float*)d_in[5];
    const float* w1     = (const float*)d_in[6];
    const float* b1     = (const float*)d_in[7];
    const float* w2     = (const float*)d_in[8];
    const float* b2     = (const float*)d_in[9];
    const float* ln1_g  = (const float*)d_in[10];
    const float* ln1_b  = (const float*)d_in[11];
    const float* ln2_g  = (const float*)d_in[12];
    const float* ln2_b  = (const float*)d_in[13];
    float* out = (float*)d_out;

    char* w = (char*)d_ws;
    size_t off = 0;
    auto alloc = [&](size_t bytes) {
        void* p = w + off;
        off += (bytes + 255) & ~(size_t)255;
        return p;
    };
    __hip_bfloat16* h_ln    = (__hip_bfloat16*)alloc(8192ull * 768 * 2);
    __hip_bfloat16* wt_qkv  = (__hip_bfloat16*)alloc(2304ull * 768 * 2);
    __hip_bfloat16* wt_proj = (__hip_bfloat16*)alloc(768ull * 768 * 2);
    __hip_bfloat16* wt1     = (__hip_bfloat16*)alloc(3072ull * 768 * 2);
    __hip_bfloat16* wt2     = (__hip_bfloat16*)alloc(768ull * 3072 * 2);
    __hip_bfloat16* qbuf    = (__hip_bfloat16*)alloc(8192ull * 768 * 2);
    __hip_bfloat16* kbuf    = (__hip_bfloat16*)alloc(8192ull * 768 * 2);
    __hip_bfloat16* vbuf    = (__hip_bfloat16*)alloc(8192ull * 768 * 2);
    __hip_bfloat16* attn_o  = (__hip_bfloat16*)alloc(8192ull * 768 * 2);
    float*          x1      = (float*)alloc(8192ull * 768 * 4);
    __hip_bfloat16* h2      = (__hip_bfloat16*)alloc(8192ull * 768 * 2);
    __hip_bfloat16* a1      = qbuf;  // alias: q/k/v/attn_o dead by FFN1

    conv_qkv<<<dim3(24, 2, 36), dim3(32, 8), 0, stream>>>(wq, wk, wv, wt_qkv);
    transpose_w<<<dim3(24, 24), dim3(32, 8), 0, stream>>>(w_proj, wt_proj, 768, 768);
    transpose_w<<<dim3(96, 24), dim3(32, 8), 0, stream>>>(w1, wt1, 768, 3072);
    transpose_w<<<dim3(24, 96), dim3(32, 8), 0, stream>>>(w2, wt2, 3072, 768);

    ln_kernel<<<8192, 256, 0, stream>>>(x, ln1_g, ln1_b, h_ln);
    gemm_kernel<1><<<dim3(18, 64), 256, 0, stream>>>(
        h_ln, wt_qkv, nullptr, nullptr, qbuf, kbuf, vbuf, 8192, 2304, 768);
    attn_kernel<<<dim3(16, 48), 256, 0, stream>>>(qbuf, kbuf, vbuf, attn_o);
    gemm_kernel<2><<<dim3(6, 64), 256, 0, stream>>>(
        attn_o, wt_proj, b_proj, x, x1, nullptr, nullptr, 8192, 768, 768);

    ln_kernel<<<8192, 256, 0, stream>>>(x1, ln2_g, ln2_b, h2);
    gemm_kernel<3><<<dim3(24, 64), 256, 0, stream>>>(
        h2, wt1, b1, nullptr, a1, nullptr, nullptr, 8192, 3072, 768);
    gemm_kernel<2><<<dim3(6, 64), 256, 0, stream>>>(
        a1, wt2, b2, x1, out, nullptr, nullptr, 8192, 768, 3072);
}

// Round 4
// 324.929 us; speedup vs baseline: 1.3068x; 1.2080x over previous
//
#include <hip/hip_runtime.h>
#include <hip/hip_bf16.h>

typedef __attribute__((ext_vector_type(8))) short bf16x8;
typedef __attribute__((ext_vector_type(4))) short bf16x4;
typedef __attribute__((ext_vector_type(4))) float f32x4;

#define AS1 __attribute__((address_space(1)))
#define AS3 __attribute__((address_space(3)))

// ---------------------------------------------------------------- LayerNorm
__global__ __launch_bounds__(256)
void ln_kernel(const float* __restrict__ x, const float* __restrict__ g,
               const float* __restrict__ b, __hip_bfloat16* __restrict__ out)
{
    const int row = blockIdx.x;
    const float* xr = x + (size_t)row * 768;
    const int t = threadIdx.x;
    float v0 = xr[t], v1 = xr[t + 256], v2 = xr[t + 512];
    float s = v0 + v1 + v2;
    float ss = v0 * v0 + v1 * v1 + v2 * v2;
#pragma unroll
    for (int off = 1; off < 64; off <<= 1) {
        s  += __shfl_xor(s, off, 64);
        ss += __shfl_xor(ss, off, 64);
    }
    __shared__ float red[8];
    const int wv = t >> 6;
    if ((t & 63) == 0) { red[wv] = s; red[wv + 4] = ss; }
    __syncthreads();
    s  = red[0] + red[1] + red[2] + red[3];
    ss = red[4] + red[5] + red[6] + red[7];
    const float mu = s * (1.0f / 768.0f);
    const float rstd = rsqrtf(ss * (1.0f / 768.0f) - mu * mu + 1e-5f);
    __hip_bfloat16* orow = out + (size_t)row * 768;
    orow[t]       = __float2bfloat16((v0 - mu) * rstd * g[t]       + b[t]);
    orow[t + 256] = __float2bfloat16((v1 - mu) * rstd * g[t + 256] + b[t + 256]);
    orow[t + 512] = __float2bfloat16((v2 - mu) * rstd * g[t + 512] + b[t + 512]);
}

// ------------------------------------------------- weight transpose f32->bf16
__global__ __launch_bounds__(256)
void transpose_w(const float* __restrict__ in, __hip_bfloat16* __restrict__ out,
                 int R, int C)
{
    __shared__ float tile[32][33];
    const int c0 = blockIdx.x * 32, r0 = blockIdx.y * 32;
    const int tx = threadIdx.x, ty = threadIdx.y;
#pragma unroll
    for (int i = 0; i < 4; i++)
        tile[ty + i * 8][tx] = in[(size_t)(r0 + ty + i * 8) * C + c0 + tx];
    __syncthreads();
#pragma unroll
    for (int i = 0; i < 4; i++)
        out[(size_t)(c0 + ty + i * 8) * R + r0 + tx] =
            __float2bfloat16(tile[tx][ty + i * 8]);
}

// ---------------------------------------------- QKV weight pack: [H,C,D] f32
__global__ __launch_bounds__(256)
void conv_qkv(const float* __restrict__ wq, const float* __restrict__ wk,
              const float* __restrict__ wv, __hip_bfloat16* __restrict__ out)
{
    const int z = blockIdx.z;
    const int mat = z / 12, h = z % 12;
    const float* w = (mat == 0) ? wq : ((mat == 1) ? wk : wv);
    __shared__ float tile[32][33];
    const int c0 = blockIdx.x * 32;
    const int d0 = blockIdx.y * 32;
    const int tx = threadIdx.x, ty = threadIdx.y;
#pragma unroll
    for (int i = 0; i < 4; i++)
        tile[ty + i * 8][tx] =
            w[(size_t)h * 768 * 64 + (size_t)(c0 + ty + i * 8) * 64 + d0 + tx];
    __syncthreads();
#pragma unroll
    for (int i = 0; i < 4; i++)
        out[(size_t)(mat * 768 + h * 64 + d0 + ty + i * 8) * 768 + c0 + tx] =
            __float2bfloat16(tile[tx][ty + i * 8]);
}

// ------------------------------------------------------------------- GEMM
// C[M,N] = A[M,K] (bf16 row-major) * Bt[N,K]^T.
// MODE 1: out -> Q [bh][t][d] (prescaled 0.125*log2e), K [bh][t][d],
//         V TRANSPOSED [bh][d][t] (bf16x4 stores along t)
// MODE 2: out f32 [M,N] = res + acc + bias
// MODE 3: out bf16 [M,N] = relu(acc + bias)
template<int MODE>
__global__ __launch_bounds__(256)
void gemm_kernel(const __hip_bfloat16* __restrict__ A,
                 const __hip_bfloat16* __restrict__ Bt,
                 const float* __restrict__ bias,
                 const float* __restrict__ res,
                 void* __restrict__ outp,
                 __hip_bfloat16* __restrict__ outK,
                 __hip_bfloat16* __restrict__ outV,
                 int M, int N, int K)
{
    __shared__ alignas(16) __hip_bfloat16 As[128 * 32];
    __shared__ alignas(16) __hip_bfloat16 Bs[128 * 32];
    const int tid = threadIdx.x;
    const int wave = tid >> 6, lane = tid & 63;
    const int m0 = blockIdx.y * 128, n0 = blockIdx.x * 128;
    const int wm = (wave >> 1) * 64, wn = (wave & 1) * 64;
    f32x4 acc[4][4] = {};

    const int srow = lane >> 2;
    const int scol = (lane & 3) * 16;

    for (int k0 = 0; k0 < K; k0 += 32) {
        __syncthreads();
#pragma unroll
        for (int c = 0; c < 2; ++c) {
            const int ch = wave + c * 4;
            const int row = ch * 16 + srow;
            const char* ga = (const char*)A  + ((size_t)(m0 + row) * K + k0) * 2 + scol;
            const char* gb = (const char*)Bt + ((size_t)(n0 + row) * K + k0) * 2 + scol;
            __builtin_amdgcn_global_load_lds((const AS1 void*)ga,
                (AS3 void*)((char*)As + ch * 1024), 16, 0, 0);
            __builtin_amdgcn_global_load_lds((const AS1 void*)gb,
                (AS3 void*)((char*)Bs + ch * 1024), 16, 0, 0);
        }
        __syncthreads();
        const int fr = lane & 15, fg = lane >> 4;
        bf16x8 af[4], bfr[4];
#pragma unroll
        for (int i = 0; i < 4; i++)
            af[i] = *(const bf16x8*)&As[(wm + i * 16 + fr) * 32 + fg * 8];
#pragma unroll
        for (int j = 0; j < 4; j++)
            bfr[j] = *(const bf16x8*)&Bs[(wn + j * 16 + fr) * 32 + fg * 8];
#pragma unroll
        for (int i = 0; i < 4; i++)
#pragma unroll
            for (int j = 0; j < 4; j++)
                acc[i][j] = __builtin_amdgcn_mfma_f32_16x16x32_bf16(
                    af[i], bfr[j], acc[i][j], 0, 0, 0);
    }

    const int fr = lane & 15, fg = lane >> 4;
#pragma unroll
    for (int j = 0; j < 4; j++) {
        const int n = n0 + wn + j * 16 + fr;
        if (MODE == 1 && n >= 1536) {
            // V transposed: vbuf[bh][d][t], vector store along t
            const int hh = (n - 1536) >> 6, dd = (n - 1536) & 63;
#pragma unroll
            for (int i = 0; i < 4; i++) {
                const int m = m0 + wm + i * 16 + fg * 4;
                const int bidx = m >> 11, tt = m & 2047;
                bf16x4 pk;
                __hip_bfloat16* pp = (__hip_bfloat16*)&pk;
#pragma unroll
                for (int r = 0; r < 4; r++)
                    pp[r] = __float2bfloat16(acc[i][j][r]);
                *(bf16x4*)&outV[(((size_t)bidx * 12 + hh) * 64 + dd) * 2048 + tt] = pk;
            }
            continue;
        }
        const float bv = (MODE == 2 || MODE == 3) ? bias[n] : 0.0f;
#pragma unroll
        for (int i = 0; i < 4; i++) {
#pragma unroll
            for (int r = 0; r < 4; r++) {
                const int m = m0 + wm + i * 16 + fg * 4 + r;
                float v = acc[i][j][r] + bv;
                if (MODE == 3) v = fmaxf(v, 0.0f);
                if (MODE == 2) {
                    ((float*)outp)[(size_t)m * N + n] = res[(size_t)m * N + n] + v;
                } else if (MODE == 1) {
                    __hip_bfloat16* dst; int nc;
                    if (n < 768) { dst = (__hip_bfloat16*)outp; nc = n;
                                   v *= 0.18033688011112042f; /* 0.125*log2e */ }
                    else         { dst = outK; nc = n - 768; }
                    const int hh = nc >> 6, dd = nc & 63;
                    const int bidx = m >> 11, tt = m & 2047;
                    dst[(((size_t)bidx * 12 + hh) * 2048 + tt) * 64 + dd] =
                        __float2bfloat16(v);
                } else {
                    ((__hip_bfloat16*)outp)[(size_t)m * N + n] = __float2bfloat16(v);
                }
            }
        }
    }
}

// ----------------------------------------------------------- causal attention
// Q,K: [B*H, 2048, 64] bf16 (Q prescaled by 0.125*log2e). V: [B*H, 64, 2048]
// bf16 (pre-transposed). out: [B*2048, 768] bf16.
// WORK-BALANCED: 32 q-tiles of 64 rows; block bx processes tiles {bx, 31-bx}
// sequentially -> every block = (bx+1)+(32-bx) = 33 kv-tile iterations, so all
// 768 blocks (3/CU) have identical duration regardless of CU assignment.
// Per pass: 4 waves x 16 q-rows. K tile [64kv][64d] and V^T tile [64d][64kv]
// XOR-swizzled in LDS (linear global_load_lds dest + inv-swizzled source).
// S^T = K*Q^T (16x16x32); O^T += V^T*P^T (16x16x16). Mask only on final tile.
__global__ __launch_bounds__(256)
void attn_kernel(const __hip_bfloat16* __restrict__ Q,
                 const __hip_bfloat16* __restrict__ Kg,
                 const __hip_bfloat16* __restrict__ Vg,
                 __hip_bfloat16* __restrict__ out)
{
    __shared__ alignas(16) char lds[32768];   // [cur][ K 8KB | V^T 8KB ]
    const int tid = threadIdx.x, wave = tid >> 6, lane = tid & 63;
    const int fr = lane & 15, fg = lane >> 4;
    const int bh = blockIdx.y, bx = blockIdx.x;
    const int b = bh / 12, h = bh % 12;
    const __hip_bfloat16* qb = Q  + (size_t)bh * 2048 * 64;
    const __hip_bfloat16* kb = Kg + (size_t)bh * 2048 * 64;
    const __hip_bfloat16* vb = Vg + (size_t)bh * 2048 * 64;   // [64 d][2048 t]

    // staging: chunk n = wave*64+lane+256r covers LDS bytes n*16..+16 (linear)
    int ksoff[2], vsoff[2];
#pragma unroll
    for (int r = 0; r < 2; r++) {
        const int n = wave * 64 + lane + 256 * r;
        const int row = n >> 3;
        const int swz = (((n & 7) << 4)) ^ ((row & 7) << 4);
        ksoff[r] = row * 128  + swz;
        vsoff[r] = row * 4096 + swz;
    }

    auto STAGE = [&](int cur, int kv0) {
        const char* kx = (const char*)kb + (size_t)kv0 * 128;
        const char* vx = (const char*)vb + (size_t)kv0 * 2;
#pragma unroll
        for (int r = 0; r < 2; r++) {
            __builtin_amdgcn_global_load_lds((const AS1 void*)(kx + ksoff[r]),
                (AS3 void*)(lds + cur * 16384 + r * 4096 + wave * 1024), 16, 0, 0);
            __builtin_amdgcn_global_load_lds((const AS1 void*)(vx + vsoff[r]),
                (AS3 void*)(lds + cur * 16384 + 8192 + r * 4096 + wave * 1024), 16, 0, 0);
        }
    };

#pragma unroll
    for (int pass = 0; pass < 2; ++pass) {
        const int g = pass ? (31 - bx) : bx;      // 64-row q-tile index
        const int q0w = g * 64 + wave * 16;       // this wave's 16 q-rows
        const int qv = q0w + fr;                  // this lane's q row

        bf16x8 qf0 = *(const bf16x8*)(qb + (size_t)qv * 64 + fg * 8);
        bf16x8 qf1 = *(const bf16x8*)(qb + (size_t)qv * 64 + 32 + fg * 8);

        f32x4 o[4] = {};
        float mrun = -1e30f, lrun = 0.f;
        const int NT = g + 1;

        STAGE(0, 0);
        __syncthreads();
        int cur = 0;

        for (int t = 0; t < NT; ++t) {
            if (t + 1 < NT) STAGE(cur ^ 1, (t + 1) << 6);
            const int kv0 = t << 6;
            const char* Kb = lds + cur * 16384;
            const char* Vb = Kb + 8192;
            // ---- S^T = K * Q^T
            bf16x8 kf[4][2];
#pragma unroll
            for (int c = 0; c < 4; c++)
#pragma unroll
                for (int hh = 0; hh < 2; hh++)
                    kf[c][hh] = *(const bf16x8*)(Kb + (16 * c + fr) * 128 +
                                ((hh * 64 + fg * 16) ^ ((fr & 7) << 4)));
            f32x4 s[4];
            __builtin_amdgcn_s_setprio(1);
#pragma unroll
            for (int c = 0; c < 4; c++) {
                f32x4 z = {};
                s[c] = __builtin_amdgcn_mfma_f32_16x16x32_bf16(
                    kf[c][0], qf0, z, 0, 0, 0);
                s[c] = __builtin_amdgcn_mfma_f32_16x16x32_bf16(
                    kf[c][1], qf1, s[c], 0, 0, 0);
            }
            __builtin_amdgcn_s_setprio(0);
            if (t == NT - 1) {   // only the diagonal tile needs masking
#pragma unroll
                for (int c = 0; c < 4; c++)
#pragma unroll
                    for (int r = 0; r < 4; r++)
                        if (kv0 + 16 * c + 4 * fg + r > qv) s[c][r] = -1e30f;
            }
            // ---- online softmax (stats per q-row = lane&15)
            float tm = -1e30f;
#pragma unroll
            for (int c = 0; c < 4; c++)
                tm = fmaxf(tm, fmaxf(fmaxf(s[c][0], s[c][1]),
                                     fmaxf(s[c][2], s[c][3])));
            tm = fmaxf(tm, __shfl_xor(tm, 16, 64));
            tm = fmaxf(tm, __shfl_xor(tm, 32, 64));
            if (!__all(tm <= mrun + 8.f)) {      // defer-max (T13)
                const float mnew = fmaxf(mrun, tm);
                const float al = exp2f(mrun - mnew);
                lrun *= al;
#pragma unroll
                for (int i = 0; i < 4; i++)
#pragma unroll
                    for (int e = 0; e < 4; e++) o[i][e] *= al;
                mrun = mnew;
            }
            bf16x4 pf[4];
            float ps = 0.f;
#pragma unroll
            for (int c = 0; c < 4; c++) {
                const float p0 = exp2f(s[c][0] - mrun), p1 = exp2f(s[c][1] - mrun);
                const float p2 = exp2f(s[c][2] - mrun), p3 = exp2f(s[c][3] - mrun);
                ps += (p0 + p1) + (p2 + p3);
                __hip_bfloat16* pp = (__hip_bfloat16*)&pf[c];
                pp[0] = __float2bfloat16(p0); pp[1] = __float2bfloat16(p1);
                pp[2] = __float2bfloat16(p2); pp[3] = __float2bfloat16(p3);
            }
            ps += __shfl_xor(ps, 16, 64);
            ps += __shfl_xor(ps, 32, 64);
            lrun += ps;
            // ---- PV: O^T += V^T * P^T
            bf16x4 vf[4][4];
#pragma unroll
            for (int i = 0; i < 4; i++)
#pragma unroll
                for (int c = 0; c < 4; c++)
                    vf[i][c] = *(const bf16x4*)(Vb + (16 * i + fr) * 128 +
                                ((32 * c + 8 * fg) ^ ((fr & 7) << 4)));
            __builtin_amdgcn_s_setprio(1);
#pragma unroll
            for (int i = 0; i < 4; i++)
#pragma unroll
                for (int c = 0; c < 4; c++)
                    o[i] = __builtin_amdgcn_mfma_f32_16x16x16bf16_1k(
                        vf[i][c], pf[c], o[i], 0, 0, 0);
            __builtin_amdgcn_s_setprio(0);
            __syncthreads();
            cur ^= 1;
        }

        const float inv = 1.0f / lrun;
        __hip_bfloat16* ob = out + ((size_t)(b * 2048 + qv)) * 768 + h * 64;
#pragma unroll
        for (int i = 0; i < 4; i++) {
            bf16x4 pk;
            __hip_bfloat16* pp = (__hip_bfloat16*)&pk;
#pragma unroll
            for (int r = 0; r < 4; r++)
                pp[r] = __float2bfloat16(o[i][r] * inv);
            *(bf16x4*)(ob + 16 * i + 4 * fg) = pk;
        }
    }
}

// ---------------------------------------------------------------------------
extern "C" void kernel_launch(void* const* d_in, const int* in_sizes, int n_in,
                              void* d_out, int out_size, void* d_ws, size_t ws_size,
                              hipStream_t stream)
{
    const float* x      = (const float*)d_in[0];
    const float* wq     = (const float*)d_in[1];
    const float* wk     = (const float*)d_in[2];
    const float* wv     = (const float*)d_in[3];
    const float* w_proj = (const float*)d_in[4];
    const float* b_proj = (const float*)d_in[5];
    const float* w1     = (const float*)d_in[6];
    const float* b1     = (const float*)d_in[7];
    const float* w2     = (const float*)d_in[8];
    const float* b2     = (const float*)d_in[9];
    const float* ln1_g  = (const float*)d_in[10];
    const float* ln1_b  = (const float*)d_in[11];
    const float* ln2_g  = (const float*)d_in[12];
    const float* ln2_b  = (const float*)d_in[13];
    float* out = (float*)d_out;

    char* w = (char*)d_ws;
    size_t off = 0;
    auto alloc = [&](size_t bytes) {
        void* p = w + off;
        off += (bytes + 255) & ~(size_t)255;
        return p;
    };
    __hip_bfloat16* h_ln    = (__hip_bfloat16*)alloc(8192ull * 768 * 2);
    __hip_bfloat16* wt_qkv  = (__hip_bfloat16*)alloc(2304ull * 768 * 2);
    __hip_bfloat16* wt_proj = (__hip_bfloat16*)alloc(768ull * 768 * 2);
    __hip_bfloat16* wt1     = (__hip_bfloat16*)alloc(3072ull * 768 * 2);
    __hip_bfloat16* wt2     = (__hip_bfloat16*)alloc(768ull * 3072 * 2);
    __hip_bfloat16* qbuf    = (__hip_bfloat16*)alloc(8192ull * 768 * 2);
    __hip_bfloat16* kbuf    = (__hip_bfloat16*)alloc(8192ull * 768 * 2);
    __hip_bfloat16* vbuf    = (__hip_bfloat16*)alloc(8192ull * 768 * 2);
    __hip_bfloat16* attn_o  = (__hip_bfloat16*)alloc(8192ull * 768 * 2);
    float*          x1      = (float*)alloc(8192ull * 768 * 4);
    __hip_bfloat16* h2      = (__hip_bfloat16*)alloc(8192ull * 768 * 2);
    __hip_bfloat16* a1      = qbuf;  // alias: q/k/v/attn_o dead by FFN1

    conv_qkv<<<dim3(24, 2, 36), dim3(32, 8), 0, stream>>>(wq, wk, wv, wt_qkv);
    transpose_w<<<dim3(24, 24), dim3(32, 8), 0, stream>>>(w_proj, wt_proj, 768, 768);
    transpose_w<<<dim3(96, 24), dim3(32, 8), 0, stream>>>(w1, wt1, 768, 3072);
    transpose_w<<<dim3(24, 96), dim3(32, 8), 0, stream>>>(w2, wt2, 3072, 768);

    ln_kernel<<<8192, 256, 0, stream>>>(x, ln1_g, ln1_b, h_ln);
    gemm_kernel<1><<<dim3(18, 64), 256, 0, stream>>>(
        h_ln, wt_qkv, nullptr, nullptr, qbuf, kbuf, vbuf, 8192, 2304, 768);
    attn_kernel<<<dim3(16, 48), 256, 0, stream>>>(qbuf, kbuf, vbuf, attn_o);
    gemm_kernel<2><<<dim3(6, 64), 256, 0, stream>>>(
        attn_o, wt_proj, b_proj, x, x1, nullptr, nullptr, 8192, 768, 768);

    ln_kernel<<<8192, 256, 0, stream>>>(x1, ln2_g, ln2_b, h2);
    gemm_kernel<3><<<dim3(24, 64), 256, 0, stream>>>(
        h2, wt1, b1, nullptr, a1, nullptr, nullptr, 8192, 3072, 768);
    gemm_kernel<2><<<dim3(6, 64), 256, 0, stream>>>(
        a1, wt2, b2, x1, out, nullptr, nullptr, 8192, 768, 3072);
}

// Round 5
// 260.632 us; speedup vs baseline: 1.6292x; 1.2467x over previous
//
#include <hip/hip_runtime.h>
#include <hip/hip_bf16.h>

typedef __attribute__((ext_vector_type(8))) short bf16x8;
typedef __attribute__((ext_vector_type(4))) short bf16x4;
typedef __attribute__((ext_vector_type(4))) float f32x4;

#define AS1 __attribute__((address_space(1)))
#define AS3 __attribute__((address_space(3)))

// ---------------------------------------------------------------- LayerNorm
__global__ __launch_bounds__(256)
void ln_kernel(const float* __restrict__ x, const float* __restrict__ g,
               const float* __restrict__ b, __hip_bfloat16* __restrict__ out)
{
    const int row = blockIdx.x;
    const float* xr = x + (size_t)row * 768;
    const int t = threadIdx.x;
    float v0 = xr[t], v1 = xr[t + 256], v2 = xr[t + 512];
    float s = v0 + v1 + v2;
    float ss = v0 * v0 + v1 * v1 + v2 * v2;
#pragma unroll
    for (int off = 1; off < 64; off <<= 1) {
        s  += __shfl_xor(s, off, 64);
        ss += __shfl_xor(ss, off, 64);
    }
    __shared__ float red[8];
    const int wv = t >> 6;
    if ((t & 63) == 0) { red[wv] = s; red[wv + 4] = ss; }
    __syncthreads();
    s  = red[0] + red[1] + red[2] + red[3];
    ss = red[4] + red[5] + red[6] + red[7];
    const float mu = s * (1.0f / 768.0f);
    const float rstd = rsqrtf(ss * (1.0f / 768.0f) - mu * mu + 1e-5f);
    __hip_bfloat16* orow = out + (size_t)row * 768;
    orow[t]       = __float2bfloat16((v0 - mu) * rstd * g[t]       + b[t]);
    orow[t + 256] = __float2bfloat16((v1 - mu) * rstd * g[t + 256] + b[t + 256]);
    orow[t + 512] = __float2bfloat16((v2 - mu) * rstd * g[t + 512] + b[t + 512]);
}

// ------------------------------------------------- weight transpose f32->bf16
__global__ __launch_bounds__(256)
void transpose_w(const float* __restrict__ in, __hip_bfloat16* __restrict__ out,
                 int R, int C)
{
    __shared__ float tile[32][33];
    const int c0 = blockIdx.x * 32, r0 = blockIdx.y * 32;
    const int tx = threadIdx.x, ty = threadIdx.y;
#pragma unroll
    for (int i = 0; i < 4; i++)
        tile[ty + i * 8][tx] = in[(size_t)(r0 + ty + i * 8) * C + c0 + tx];
    __syncthreads();
#pragma unroll
    for (int i = 0; i < 4; i++)
        out[(size_t)(c0 + ty + i * 8) * R + r0 + tx] =
            __float2bfloat16(tile[tx][ty + i * 8]);
}

// ---------------------------------------------- QKV weight pack: [H,C,D] f32
__global__ __launch_bounds__(256)
void conv_qkv(const float* __restrict__ wq, const float* __restrict__ wk,
              const float* __restrict__ wv, __hip_bfloat16* __restrict__ out)
{
    const int z = blockIdx.z;
    const int mat = z / 12, h = z % 12;
    const float* w = (mat == 0) ? wq : ((mat == 1) ? wk : wv);
    __shared__ float tile[32][33];
    const int c0 = blockIdx.x * 32;
    const int d0 = blockIdx.y * 32;
    const int tx = threadIdx.x, ty = threadIdx.y;
#pragma unroll
    for (int i = 0; i < 4; i++)
        tile[ty + i * 8][tx] =
            w[(size_t)h * 768 * 64 + (size_t)(c0 + ty + i * 8) * 64 + d0 + tx];
    __syncthreads();
#pragma unroll
    for (int i = 0; i < 4; i++)
        out[(size_t)(mat * 768 + h * 64 + d0 + ty + i * 8) * 768 + c0 + tx] =
            __float2bfloat16(tile[tx][ty + i * 8]);
}

// ------------------------------------------------------------------- GEMM
// C[M,N] = A[M,K] (bf16 row-major) * Bt[N,K]^T. BK=64, XOR-swizzled LDS tiles
// (T2: 128B rows, byte ^= (row&7)<<4, pre-swizzled global_load_lds source),
// XCD-chunked work remap (T1: work = (hw%8)*q + hw/8, grids all %8==0).
// MODE 1: out -> Q [bh][t][d] (prescaled 0.125*log2e), K [bh][t][d],
//         V TRANSPOSED [bh][d][t] (bf16x4 stores along t)
// MODE 2: out f32 [M,N] = res + acc + bias
// MODE 3: out bf16 [M,N] = relu(acc + bias)
template<int MODE>
__global__ __launch_bounds__(256)
void gemm_kernel(const __hip_bfloat16* __restrict__ A,
                 const __hip_bfloat16* __restrict__ Bt,
                 const float* __restrict__ bias,
                 const float* __restrict__ res,
                 void* __restrict__ outp,
                 __hip_bfloat16* __restrict__ outK,
                 __hip_bfloat16* __restrict__ outV,
                 int M, int N, int K)
{
    __shared__ alignas(16) char As[128 * 128];   // [128 m][64 k] bf16, swizzled
    __shared__ alignas(16) char Bs[128 * 128];   // [128 n][64 k] bf16, swizzled
    const int tid = threadIdx.x;
    const int wave = tid >> 6, lane = tid & 63;

    // T1: XCD-chunked remap of linearized workgroup id
    const int nwgx = gridDim.x;
    const int hw = blockIdx.x + nwgx * blockIdx.y;
    const int nwg = nwgx * gridDim.y;
    const int q8 = nwg >> 3;                    // all grids divisible by 8
    const int work = (hw & 7) * q8 + (hw >> 3);
    const int m0 = (work / nwgx) * 128, n0 = (work % nwgx) * 128;

    const int wm = (wave >> 1) * 64, wn = (wave & 1) * 64;
    f32x4 acc[4][4] = {};

    // staging: chunk n = tid + 256r covers LDS bytes n*16..+16 (linear dest)
    int soff[4];
#pragma unroll
    for (int r = 0; r < 4; r++) {
        const int n = tid + 256 * r;
        const int row = n >> 3;
        soff[r] = row * (K * 2) + ((((n & 7) << 4)) ^ ((row & 7) << 4));
    }

    const int fr = lane & 15, fg = lane >> 4;

    for (int k0 = 0; k0 < K; k0 += 64) {
        __syncthreads();
        const char* ga = (const char*)A  + (size_t)m0 * K * 2 + k0 * 2;
        const char* gb = (const char*)Bt + (size_t)n0 * K * 2 + k0 * 2;
#pragma unroll
        for (int r = 0; r < 4; r++) {
            __builtin_amdgcn_global_load_lds((const AS1 void*)(ga + soff[r]),
                (AS3 void*)(As + r * 4096 + tid * 16), 16, 0, 0);
            __builtin_amdgcn_global_load_lds((const AS1 void*)(gb + soff[r]),
                (AS3 void*)(Bs + r * 4096 + tid * 16), 16, 0, 0);
        }
        __syncthreads();
        bf16x8 af[4][2], bfr[4][2];
#pragma unroll
        for (int i = 0; i < 4; i++)
#pragma unroll
            for (int ks = 0; ks < 2; ks++)
                af[i][ks] = *(const bf16x8*)(As + (wm + i * 16 + fr) * 128 +
                            ((fg * 16 + ks * 64) ^ ((fr & 7) << 4)));
#pragma unroll
        for (int j = 0; j < 4; j++)
#pragma unroll
            for (int ks = 0; ks < 2; ks++)
                bfr[j][ks] = *(const bf16x8*)(Bs + (wn + j * 16 + fr) * 128 +
                             ((fg * 16 + ks * 64) ^ ((fr & 7) << 4)));
        __builtin_amdgcn_s_setprio(1);
#pragma unroll
        for (int ks = 0; ks < 2; ks++)
#pragma unroll
            for (int i = 0; i < 4; i++)
#pragma unroll
                for (int j = 0; j < 4; j++)
                    acc[i][j] = __builtin_amdgcn_mfma_f32_16x16x32_bf16(
                        af[i][ks], bfr[j][ks], acc[i][j], 0, 0, 0);
        __builtin_amdgcn_s_setprio(0);
    }

#pragma unroll
    for (int j = 0; j < 4; j++) {
        const int n = n0 + wn + j * 16 + fr;
        if (MODE == 1 && n >= 1536) {
            // V transposed: vbuf[bh][d][t], vector store along t
            const int hh = (n - 1536) >> 6, dd = (n - 1536) & 63;
#pragma unroll
            for (int i = 0; i < 4; i++) {
                const int m = m0 + wm + i * 16 + fg * 4;
                const int bidx = m >> 11, tt = m & 2047;
                bf16x4 pk;
                __hip_bfloat16* pp = (__hip_bfloat16*)&pk;
#pragma unroll
                for (int r = 0; r < 4; r++)
                    pp[r] = __float2bfloat16(acc[i][j][r]);
                *(bf16x4*)&outV[(((size_t)bidx * 12 + hh) * 64 + dd) * 2048 + tt] = pk;
            }
            continue;
        }
        const float bv = (MODE == 2 || MODE == 3) ? bias[n] : 0.0f;
#pragma unroll
        for (int i = 0; i < 4; i++) {
#pragma unroll
            for (int r = 0; r < 4; r++) {
                const int m = m0 + wm + i * 16 + fg * 4 + r;
                float v = acc[i][j][r] + bv;
                if (MODE == 3) v = fmaxf(v, 0.0f);
                if (MODE == 2) {
                    ((float*)outp)[(size_t)m * N + n] = res[(size_t)m * N + n] + v;
                } else if (MODE == 1) {
                    __hip_bfloat16* dst; int nc;
                    if (n < 768) { dst = (__hip_bfloat16*)outp; nc = n;
                                   v *= 0.18033688011112042f; /* 0.125*log2e */ }
                    else         { dst = outK; nc = n - 768; }
                    const int hh = nc >> 6, dd = nc & 63;
                    const int bidx = m >> 11, tt = m & 2047;
                    dst[(((size_t)bidx * 12 + hh) * 2048 + tt) * 64 + dd] =
                        __float2bfloat16(v);
                } else {
                    ((__hip_bfloat16*)outp)[(size_t)m * N + n] = __float2bfloat16(v);
                }
            }
        }
    }
}

// ----------------------------------------------------------- causal attention
// (unchanged from R4 — work-balanced paired q-tiles, 33 kv-iters/block)
__global__ __launch_bounds__(256)
void attn_kernel(const __hip_bfloat16* __restrict__ Q,
                 const __hip_bfloat16* __restrict__ Kg,
                 const __hip_bfloat16* __restrict__ Vg,
                 __hip_bfloat16* __restrict__ out)
{
    __shared__ alignas(16) char lds[32768];   // [cur][ K 8KB | V^T 8KB ]
    const int tid = threadIdx.x, wave = tid >> 6, lane = tid & 63;
    const int fr = lane & 15, fg = lane >> 4;
    const int bh = blockIdx.y, bx = blockIdx.x;
    const int b = bh / 12, h = bh % 12;
    const __hip_bfloat16* qb = Q  + (size_t)bh * 2048 * 64;
    const __hip_bfloat16* kb = Kg + (size_t)bh * 2048 * 64;
    const __hip_bfloat16* vb = Vg + (size_t)bh * 2048 * 64;   // [64 d][2048 t]

    int ksoff[2], vsoff[2];
#pragma unroll
    for (int r = 0; r < 2; r++) {
        const int n = wave * 64 + lane + 256 * r;
        const int row = n >> 3;
        const int swz = (((n & 7) << 4)) ^ ((row & 7) << 4);
        ksoff[r] = row * 128  + swz;
        vsoff[r] = row * 4096 + swz;
    }

    auto STAGE = [&](int cur, int kv0) {
        const char* kx = (const char*)kb + (size_t)kv0 * 128;
        const char* vx = (const char*)vb + (size_t)kv0 * 2;
#pragma unroll
        for (int r = 0; r < 2; r++) {
            __builtin_amdgcn_global_load_lds((const AS1 void*)(kx + ksoff[r]),
                (AS3 void*)(lds + cur * 16384 + r * 4096 + wave * 1024), 16, 0, 0);
            __builtin_amdgcn_global_load_lds((const AS1 void*)(vx + vsoff[r]),
                (AS3 void*)(lds + cur * 16384 + 8192 + r * 4096 + wave * 1024), 16, 0, 0);
        }
    };

#pragma unroll
    for (int pass = 0; pass < 2; ++pass) {
        const int g = pass ? (31 - bx) : bx;
        const int q0w = g * 64 + wave * 16;
        const int qv = q0w + fr;

        bf16x8 qf0 = *(const bf16x8*)(qb + (size_t)qv * 64 + fg * 8);
        bf16x8 qf1 = *(const bf16x8*)(qb + (size_t)qv * 64 + 32 + fg * 8);

        f32x4 o[4] = {};
        float mrun = -1e30f, lrun = 0.f;
        const int NT = g + 1;

        STAGE(0, 0);
        __syncthreads();
        int cur = 0;

        for (int t = 0; t < NT; ++t) {
            if (t + 1 < NT) STAGE(cur ^ 1, (t + 1) << 6);
            const int kv0 = t << 6;
            const char* Kb = lds + cur * 16384;
            const char* Vb = Kb + 8192;
            bf16x8 kf[4][2];
#pragma unroll
            for (int c = 0; c < 4; c++)
#pragma unroll
                for (int hh = 0; hh < 2; hh++)
                    kf[c][hh] = *(const bf16x8*)(Kb + (16 * c + fr) * 128 +
                                ((hh * 64 + fg * 16) ^ ((fr & 7) << 4)));
            f32x4 s[4];
            __builtin_amdgcn_s_setprio(1);
#pragma unroll
            for (int c = 0; c < 4; c++) {
                f32x4 z = {};
                s[c] = __builtin_amdgcn_mfma_f32_16x16x32_bf16(
                    kf[c][0], qf0, z, 0, 0, 0);
                s[c] = __builtin_amdgcn_mfma_f32_16x16x32_bf16(
                    kf[c][1], qf1, s[c], 0, 0, 0);
            }
            __builtin_amdgcn_s_setprio(0);
            if (t == NT - 1) {
#pragma unroll
                for (int c = 0; c < 4; c++)
#pragma unroll
                    for (int r = 0; r < 4; r++)
                        if (kv0 + 16 * c + 4 * fg + r > qv) s[c][r] = -1e30f;
            }
            float tm = -1e30f;
#pragma unroll
            for (int c = 0; c < 4; c++)
                tm = fmaxf(tm, fmaxf(fmaxf(s[c][0], s[c][1]),
                                     fmaxf(s[c][2], s[c][3])));
            tm = fmaxf(tm, __shfl_xor(tm, 16, 64));
            tm = fmaxf(tm, __shfl_xor(tm, 32, 64));
            if (!__all(tm <= mrun + 8.f)) {      // defer-max (T13)
                const float mnew = fmaxf(mrun, tm);
                const float al = exp2f(mrun - mnew);
                lrun *= al;
#pragma unroll
                for (int i = 0; i < 4; i++)
#pragma unroll
                    for (int e = 0; e < 4; e++) o[i][e] *= al;
                mrun = mnew;
            }
            bf16x4 pf[4];
            float ps = 0.f;
#pragma unroll
            for (int c = 0; c < 4; c++) {
                const float p0 = exp2f(s[c][0] - mrun), p1 = exp2f(s[c][1] - mrun);
                const float p2 = exp2f(s[c][2] - mrun), p3 = exp2f(s[c][3] - mrun);
                ps += (p0 + p1) + (p2 + p3);
                __hip_bfloat16* pp = (__hip_bfloat16*)&pf[c];
                pp[0] = __float2bfloat16(p0); pp[1] = __float2bfloat16(p1);
                pp[2] = __float2bfloat16(p2); pp[3] = __float2bfloat16(p3);
            }
            ps += __shfl_xor(ps, 16, 64);
            ps += __shfl_xor(ps, 32, 64);
            lrun += ps;
            bf16x4 vf[4][4];
#pragma unroll
            for (int i = 0; i < 4; i++)
#pragma unroll
                for (int c = 0; c < 4; c++)
                    vf[i][c] = *(const bf16x4*)(Vb + (16 * i + fr) * 128 +
                                ((32 * c + 8 * fg) ^ ((fr & 7) << 4)));
            __builtin_amdgcn_s_setprio(1);
#pragma unroll
            for (int i = 0; i < 4; i++)
#pragma unroll
                for (int c = 0; c < 4; c++)
                    o[i] = __builtin_amdgcn_mfma_f32_16x16x16bf16_1k(
                        vf[i][c], pf[c], o[i], 0, 0, 0);
            __builtin_amdgcn_s_setprio(0);
            __syncthreads();
            cur ^= 1;
        }

        const float inv = 1.0f / lrun;
        __hip_bfloat16* ob = out + ((size_t)(b * 2048 + qv)) * 768 + h * 64;
#pragma unroll
        for (int i = 0; i < 4; i++) {
            bf16x4 pk;
            __hip_bfloat16* pp = (__hip_bfloat16*)&pk;
#pragma unroll
            for (int r = 0; r < 4; r++)
                pp[r] = __float2bfloat16(o[i][r] * inv);
            *(bf16x4*)(ob + 16 * i + 4 * fg) = pk;
        }
    }
}

// ---------------------------------------------------------------------------
extern "C" void kernel_launch(void* const* d_in, const int* in_sizes, int n_in,
                              void* d_out, int out_size, void* d_ws, size_t ws_size,
                              hipStream_t stream)
{
    const float* x      = (const float*)d_in[0];
    const float* wq     = (const float*)d_in[1];
    const float* wk     = (const float*)d_in[2];
    const float* wv     = (const float*)d_in[3];
    const float* w_proj = (const float*)d_in[4];
    const float* b_proj = (const float*)d_in[5];
    const float* w1     = (const float*)d_in[6];
    const float* b1     = (const float*)d_in[7];
    const float* w2     = (const float*)d_in[8];
    const float* b2     = (const float*)d_in[9];
    const float* ln1_g  = (const float*)d_in[10];
    const float* ln1_b  = (const float*)d_in[11];
    const float* ln2_g  = (const float*)d_in[12];
    const float* ln2_b  = (const float*)d_in[13];
    float* out = (float*)d_out;

    char* w = (char*)d_ws;
    size_t off = 0;
    auto alloc = [&](size_t bytes) {
        void* p = w + off;
        off += (bytes + 255) & ~(size_t)255;
        return p;
    };
    __hip_bfloat16* h_ln    = (__hip_bfloat16*)alloc(8192ull * 768 * 2);
    __hip_bfloat16* wt_qkv  = (__hip_bfloat16*)alloc(2304ull * 768 * 2);
    __hip_bfloat16* wt_proj = (__hip_bfloat16*)alloc(768ull * 768 * 2);
    __hip_bfloat16* wt1     = (__hip_bfloat16*)alloc(3072ull * 768 * 2);
    __hip_bfloat16* wt2     = (__hip_bfloat16*)alloc(768ull * 3072 * 2);
    __hip_bfloat16* qbuf    = (__hip_bfloat16*)alloc(8192ull * 768 * 2);
    __hip_bfloat16* kbuf    = (__hip_bfloat16*)alloc(8192ull * 768 * 2);
    __hip_bfloat16* vbuf    = (__hip_bfloat16*)alloc(8192ull * 768 * 2);
    __hip_bfloat16* attn_o  = (__hip_bfloat16*)alloc(8192ull * 768 * 2);
    float*          x1      = (float*)alloc(8192ull * 768 * 4);
    __hip_bfloat16* h2      = (__hip_bfloat16*)alloc(8192ull * 768 * 2);
    __hip_bfloat16* a1      = qbuf;  // alias: q/k/v/attn_o dead by FFN1

    conv_qkv<<<dim3(24, 2, 36), dim3(32, 8), 0, stream>>>(wq, wk, wv, wt_qkv);
    transpose_w<<<dim3(24, 24), dim3(32, 8), 0, stream>>>(w_proj, wt_proj, 768, 768);
    transpose_w<<<dim3(96, 24), dim3(32, 8), 0, stream>>>(w1, wt1, 768, 3072);
    transpose_w<<<dim3(24, 96), dim3(32, 8), 0, stream>>>(w2, wt2, 3072, 768);

    ln_kernel<<<8192, 256, 0, stream>>>(x, ln1_g, ln1_b, h_ln);
    gemm_kernel<1><<<dim3(18, 64), 256, 0, stream>>>(
        h_ln, wt_qkv, nullptr, nullptr, qbuf, kbuf, vbuf, 8192, 2304, 768);
    attn_kernel<<<dim3(16, 48), 256, 0, stream>>>(qbuf, kbuf, vbuf, attn_o);
    gemm_kernel<2><<<dim3(6, 64), 256, 0, stream>>>(
        attn_o, wt_proj, b_proj, x, x1, nullptr, nullptr, 8192, 768, 768);

    ln_kernel<<<8192, 256, 0, stream>>>(x1, ln2_g, ln2_b, h2);
    gemm_kernel<3><<<dim3(24, 64), 256, 0, stream>>>(
        h2, wt1, b1, nullptr, a1, nullptr, nullptr, 8192, 3072, 768);
    gemm_kernel<2><<<dim3(6, 64), 256, 0, stream>>>(
        a1, wt2, b2, x1, out, nullptr, nullptr, 8192, 768, 3072);
}

// Round 6
// 258.295 us; speedup vs baseline: 1.6439x; 1.0090x over previous
//
#include <hip/hip_runtime.h>
#include <hip/hip_bf16.h>

typedef __attribute__((ext_vector_type(8))) short bf16x8;
typedef __attribute__((ext_vector_type(4))) short bf16x4;
typedef __attribute__((ext_vector_type(4))) float f32x4;

#define AS1 __attribute__((address_space(1)))
#define AS3 __attribute__((address_space(3)))

// ---------------------------------------------------------------- LayerNorm
__global__ __launch_bounds__(256)
void ln_kernel(const float* __restrict__ x, const float* __restrict__ g,
               const float* __restrict__ b, __hip_bfloat16* __restrict__ out)
{
    const int row = blockIdx.x;
    const float* xr = x + (size_t)row * 768;
    const int t = threadIdx.x;
    float v0 = xr[t], v1 = xr[t + 256], v2 = xr[t + 512];
    float s = v0 + v1 + v2;
    float ss = v0 * v0 + v1 * v1 + v2 * v2;
#pragma unroll
    for (int off = 1; off < 64; off <<= 1) {
        s  += __shfl_xor(s, off, 64);
        ss += __shfl_xor(ss, off, 64);
    }
    __shared__ float red[8];
    const int wv = t >> 6;
    if ((t & 63) == 0) { red[wv] = s; red[wv + 4] = ss; }
    __syncthreads();
    s  = red[0] + red[1] + red[2] + red[3];
    ss = red[4] + red[5] + red[6] + red[7];
    const float mu = s * (1.0f / 768.0f);
    const float rstd = rsqrtf(ss * (1.0f / 768.0f) - mu * mu + 1e-5f);
    __hip_bfloat16* orow = out + (size_t)row * 768;
    orow[t]       = __float2bfloat16((v0 - mu) * rstd * g[t]       + b[t]);
    orow[t + 256] = __float2bfloat16((v1 - mu) * rstd * g[t + 256] + b[t + 256]);
    orow[t + 512] = __float2bfloat16((v2 - mu) * rstd * g[t + 512] + b[t + 512]);
}

// ------------------------------------------------- weight transpose f32->bf16
__global__ __launch_bounds__(256)
void transpose_w(const float* __restrict__ in, __hip_bfloat16* __restrict__ out,
                 int R, int C)
{
    __shared__ float tile[32][33];
    const int c0 = blockIdx.x * 32, r0 = blockIdx.y * 32;
    const int tx = threadIdx.x, ty = threadIdx.y;
#pragma unroll
    for (int i = 0; i < 4; i++)
        tile[ty + i * 8][tx] = in[(size_t)(r0 + ty + i * 8) * C + c0 + tx];
    __syncthreads();
#pragma unroll
    for (int i = 0; i < 4; i++)
        out[(size_t)(c0 + ty + i * 8) * R + r0 + tx] =
            __float2bfloat16(tile[tx][ty + i * 8]);
}

// ---------------------------------------------- QKV weight pack: [H,C,D] f32
__global__ __launch_bounds__(256)
void conv_qkv(const float* __restrict__ wq, const float* __restrict__ wk,
              const float* __restrict__ wv, __hip_bfloat16* __restrict__ out)
{
    const int z = blockIdx.z;
    const int mat = z / 12, h = z % 12;
    const float* w = (mat == 0) ? wq : ((mat == 1) ? wk : wv);
    __shared__ float tile[32][33];
    const int c0 = blockIdx.x * 32;
    const int d0 = blockIdx.y * 32;
    const int tx = threadIdx.x, ty = threadIdx.y;
#pragma unroll
    for (int i = 0; i < 4; i++)
        tile[ty + i * 8][tx] =
            w[(size_t)h * 768 * 64 + (size_t)(c0 + ty + i * 8) * 64 + d0 + tx];
    __syncthreads();
#pragma unroll
    for (int i = 0; i < 4; i++)
        out[(size_t)(mat * 768 + h * 64 + d0 + ty + i * 8) * 768 + c0 + tx] =
            __float2bfloat16(tile[tx][ty + i * 8]);
}

// ------------------------------------------------------------------- GEMM
// C[M,N] = A[M,K] (bf16 row-major) * Bt[N,K]^T. BK=64, XOR-swizzled LDS tiles
// (T2), XCD-chunked work remap (T1). Unchanged from R5.
template<int MODE>
__global__ __launch_bounds__(256)
void gemm_kernel(const __hip_bfloat16* __restrict__ A,
                 const __hip_bfloat16* __restrict__ Bt,
                 const float* __restrict__ bias,
                 const float* __restrict__ res,
                 void* __restrict__ outp,
                 __hip_bfloat16* __restrict__ outK,
                 __hip_bfloat16* __restrict__ outV,
                 int M, int N, int K)
{
    __shared__ alignas(16) char As[128 * 128];   // [128 m][64 k] bf16, swizzled
    __shared__ alignas(16) char Bs[128 * 128];   // [128 n][64 k] bf16, swizzled
    const int tid = threadIdx.x;
    const int wave = tid >> 6, lane = tid & 63;

    // T1: XCD-chunked remap of linearized workgroup id
    const int nwgx = gridDim.x;
    const int hw = blockIdx.x + nwgx * blockIdx.y;
    const int nwg = nwgx * gridDim.y;
    const int q8 = nwg >> 3;                    // all grids divisible by 8
    const int work = (hw & 7) * q8 + (hw >> 3);
    const int m0 = (work / nwgx) * 128, n0 = (work % nwgx) * 128;

    const int wm = (wave >> 1) * 64, wn = (wave & 1) * 64;
    f32x4 acc[4][4] = {};

    // staging: chunk n = tid + 256r covers LDS bytes n*16..+16 (linear dest)
    int soff[4];
#pragma unroll
    for (int r = 0; r < 4; r++) {
        const int n = tid + 256 * r;
        const int row = n >> 3;
        soff[r] = row * (K * 2) + ((((n & 7) << 4)) ^ ((row & 7) << 4));
    }

    const int fr = lane & 15, fg = lane >> 4;

    for (int k0 = 0; k0 < K; k0 += 64) {
        __syncthreads();
        const char* ga = (const char*)A  + (size_t)m0 * K * 2 + k0 * 2;
        const char* gb = (const char*)Bt + (size_t)n0 * K * 2 + k0 * 2;
#pragma unroll
        for (int r = 0; r < 4; r++) {
            __builtin_amdgcn_global_load_lds((const AS1 void*)(ga + soff[r]),
                (AS3 void*)(As + r * 4096 + tid * 16), 16, 0, 0);
            __builtin_amdgcn_global_load_lds((const AS1 void*)(gb + soff[r]),
                (AS3 void*)(Bs + r * 4096 + tid * 16), 16, 0, 0);
        }
        __syncthreads();
        bf16x8 af[4][2], bfr[4][2];
#pragma unroll
        for (int i = 0; i < 4; i++)
#pragma unroll
            for (int ks = 0; ks < 2; ks++)
                af[i][ks] = *(const bf16x8*)(As + (wm + i * 16 + fr) * 128 +
                            ((fg * 16 + ks * 64) ^ ((fr & 7) << 4)));
#pragma unroll
        for (int j = 0; j < 4; j++)
#pragma unroll
            for (int ks = 0; ks < 2; ks++)
                bfr[j][ks] = *(const bf16x8*)(Bs + (wn + j * 16 + fr) * 128 +
                             ((fg * 16 + ks * 64) ^ ((fr & 7) << 4)));
        __builtin_amdgcn_s_setprio(1);
#pragma unroll
        for (int ks = 0; ks < 2; ks++)
#pragma unroll
            for (int i = 0; i < 4; i++)
#pragma unroll
                for (int j = 0; j < 4; j++)
                    acc[i][j] = __builtin_amdgcn_mfma_f32_16x16x32_bf16(
                        af[i][ks], bfr[j][ks], acc[i][j], 0, 0, 0);
        __builtin_amdgcn_s_setprio(0);
    }

#pragma unroll
    for (int j = 0; j < 4; j++) {
        const int n = n0 + wn + j * 16 + fr;
        if (MODE == 1 && n >= 1536) {
            // V transposed: vbuf[bh][d][t], vector store along t
            const int hh = (n - 1536) >> 6, dd = (n - 1536) & 63;
#pragma unroll
            for (int i = 0; i < 4; i++) {
                const int m = m0 + wm + i * 16 + fg * 4;
                const int bidx = m >> 11, tt = m & 2047;
                bf16x4 pk;
                __hip_bfloat16* pp = (__hip_bfloat16*)&pk;
#pragma unroll
                for (int r = 0; r < 4; r++)
                    pp[r] = __float2bfloat16(acc[i][j][r]);
                *(bf16x4*)&outV[(((size_t)bidx * 12 + hh) * 64 + dd) * 2048 + tt] = pk;
            }
            continue;
        }
        const float bv = (MODE == 2 || MODE == 3) ? bias[n] : 0.0f;
#pragma unroll
        for (int i = 0; i < 4; i++) {
#pragma unroll
            for (int r = 0; r < 4; r++) {
                const int m = m0 + wm + i * 16 + fg * 4 + r;
                float v = acc[i][j][r] + bv;
                if (MODE == 3) v = fmaxf(v, 0.0f);
                if (MODE == 2) {
                    ((float*)outp)[(size_t)m * N + n] = res[(size_t)m * N + n] + v;
                } else if (MODE == 1) {
                    __hip_bfloat16* dst; int nc;
                    if (n < 768) { dst = (__hip_bfloat16*)outp; nc = n;
                                   v *= 0.18033688011112042f; /* 0.125*log2e */ }
                    else         { dst = outK; nc = n - 768; }
                    const int hh = nc >> 6, dd = nc & 63;
                    const int bidx = m >> 11, tt = m & 2047;
                    dst[(((size_t)bidx * 12 + hh) * 2048 + tt) * 64 + dd] =
                        __float2bfloat16(v);
                } else {
                    ((__hip_bfloat16*)outp)[(size_t)m * N + n] = __float2bfloat16(v);
                }
            }
        }
    }
}

// ----------------------------------------------------------- causal attention
// Work-balanced paired q-tiles (33 kv-iters/block) + XCD-LOCAL HEAD MAPPING:
// all 16 blocks of one (b,h) land on the same XCD (id%8 round-robin model), so
// each XCD's L2 holds 6 heads' K/V (3 MB < 4 MB) and K/V is HBM-fetched once.
__global__ __launch_bounds__(256)
void attn_kernel(const __hip_bfloat16* __restrict__ Q,
                 const __hip_bfloat16* __restrict__ Kg,
                 const __hip_bfloat16* __restrict__ Vg,
                 __hip_bfloat16* __restrict__ out)
{
    __shared__ alignas(16) char lds[32768];   // [cur][ K 8KB | V^T 8KB ]
    const int tid = threadIdx.x, wave = tid >> 6, lane = tid & 63;
    const int fr = lane & 15, fg = lane >> 4;

    // XCD-local head mapping: grid is (16, 48), hw = bx' + 16*bh'.
    const int hw = blockIdx.x + 16 * blockIdx.y;
    const int xcd = hw & 7, chunk = hw >> 3;      // 96 chunks per XCD
    const int bh = xcd * 6 + (chunk >> 4);        // 6 heads per XCD
    const int bx = chunk & 15;                    // 16 q-blocks per head

    const int b = bh / 12, h = bh % 12;
    const __hip_bfloat16* qb = Q  + (size_t)bh * 2048 * 64;
    const __hip_bfloat16* kb = Kg + (size_t)bh * 2048 * 64;
    const __hip_bfloat16* vb = Vg + (size_t)bh * 2048 * 64;   // [64 d][2048 t]

    int ksoff[2], vsoff[2];
#pragma unroll
    for (int r = 0; r < 2; r++) {
        const int n = wave * 64 + lane + 256 * r;
        const int row = n >> 3;
        const int swz = (((n & 7) << 4)) ^ ((row & 7) << 4);
        ksoff[r] = row * 128  + swz;
        vsoff[r] = row * 4096 + swz;
    }

    auto STAGE = [&](int cur, int kv0) {
        const char* kx = (const char*)kb + (size_t)kv0 * 128;
        const char* vx = (const char*)vb + (size_t)kv0 * 2;
#pragma unroll
        for (int r = 0; r < 2; r++) {
            __builtin_amdgcn_global_load_lds((const AS1 void*)(kx + ksoff[r]),
                (AS3 void*)(lds + cur * 16384 + r * 4096 + wave * 1024), 16, 0, 0);
            __builtin_amdgcn_global_load_lds((const AS1 void*)(vx + vsoff[r]),
                (AS3 void*)(lds + cur * 16384 + 8192 + r * 4096 + wave * 1024), 16, 0, 0);
        }
    };

#pragma unroll
    for (int pass = 0; pass < 2; ++pass) {
        const int g = pass ? (31 - bx) : bx;
        const int q0w = g * 64 + wave * 16;
        const int qv = q0w + fr;

        bf16x8 qf0 = *(const bf16x8*)(qb + (size_t)qv * 64 + fg * 8);
        bf16x8 qf1 = *(const bf16x8*)(qb + (size_t)qv * 64 + 32 + fg * 8);

        f32x4 o[4] = {};
        float mrun = -1e30f, lrun = 0.f;
        const int NT = g + 1;

        STAGE(0, 0);
        __syncthreads();
        int cur = 0;

        for (int t = 0; t < NT; ++t) {
            if (t + 1 < NT) STAGE(cur ^ 1, (t + 1) << 6);
            const int kv0 = t << 6;
            const char* Kb = lds + cur * 16384;
            const char* Vb = Kb + 8192;
            bf16x8 kf[4][2];
#pragma unroll
            for (int c = 0; c < 4; c++)
#pragma unroll
                for (int hh = 0; hh < 2; hh++)
                    kf[c][hh] = *(const bf16x8*)(Kb + (16 * c + fr) * 128 +
                                ((hh * 64 + fg * 16) ^ ((fr & 7) << 4)));
            f32x4 s[4];
            __builtin_amdgcn_s_setprio(1);
#pragma unroll
            for (int c = 0; c < 4; c++) {
                f32x4 z = {};
                s[c] = __builtin_amdgcn_mfma_f32_16x16x32_bf16(
                    kf[c][0], qf0, z, 0, 0, 0);
                s[c] = __builtin_amdgcn_mfma_f32_16x16x32_bf16(
                    kf[c][1], qf1, s[c], 0, 0, 0);
            }
            __builtin_amdgcn_s_setprio(0);
            if (t == NT - 1) {
#pragma unroll
                for (int c = 0; c < 4; c++)
#pragma unroll
                    for (int r = 0; r < 4; r++)
                        if (kv0 + 16 * c + 4 * fg + r > qv) s[c][r] = -1e30f;
            }
            float tm = -1e30f;
#pragma unroll
            for (int c = 0; c < 4; c++)
                tm = fmaxf(tm, fmaxf(fmaxf(s[c][0], s[c][1]),
                                     fmaxf(s[c][2], s[c][3])));
            tm = fmaxf(tm, __shfl_xor(tm, 16, 64));
            tm = fmaxf(tm, __shfl_xor(tm, 32, 64));
            if (!__all(tm <= mrun + 8.f)) {      // defer-max (T13)
                const float mnew = fmaxf(mrun, tm);
                const float al = exp2f(mrun - mnew);
                lrun *= al;
#pragma unroll
                for (int i = 0; i < 4; i++)
#pragma unroll
                    for (int e = 0; e < 4; e++) o[i][e] *= al;
                mrun = mnew;
            }
            bf16x4 pf[4];
            float ps = 0.f;
#pragma unroll
            for (int c = 0; c < 4; c++) {
                const float p0 = exp2f(s[c][0] - mrun), p1 = exp2f(s[c][1] - mrun);
                const float p2 = exp2f(s[c][2] - mrun), p3 = exp2f(s[c][3] - mrun);
                ps += (p0 + p1) + (p2 + p3);
                __hip_bfloat16* pp = (__hip_bfloat16*)&pf[c];
                pp[0] = __float2bfloat16(p0); pp[1] = __float2bfloat16(p1);
                pp[2] = __float2bfloat16(p2); pp[3] = __float2bfloat16(p3);
            }
            ps += __shfl_xor(ps, 16, 64);
            ps += __shfl_xor(ps, 32, 64);
            lrun += ps;
            bf16x4 vf[4][4];
#pragma unroll
            for (int i = 0; i < 4; i++)
#pragma unroll
                for (int c = 0; c < 4; c++)
                    vf[i][c] = *(const bf16x4*)(Vb + (16 * i + fr) * 128 +
                                ((32 * c + 8 * fg) ^ ((fr & 7) << 4)));
            __builtin_amdgcn_s_setprio(1);
#pragma unroll
            for (int i = 0; i < 4; i++)
#pragma unroll
                for (int c = 0; c < 4; c++)
                    o[i] = __builtin_amdgcn_mfma_f32_16x16x16bf16_1k(
                        vf[i][c], pf[c], o[i], 0, 0, 0);
            __builtin_amdgcn_s_setprio(0);
            __syncthreads();
            cur ^= 1;
        }

        const float inv = 1.0f / lrun;
        __hip_bfloat16* ob = out + ((size_t)(b * 2048 + qv)) * 768 + h * 64;
#pragma unroll
        for (int i = 0; i < 4; i++) {
            bf16x4 pk;
            __hip_bfloat16* pp = (__hip_bfloat16*)&pk;
#pragma unroll
            for (int r = 0; r < 4; r++)
                pp[r] = __float2bfloat16(o[i][r] * inv);
            *(bf16x4*)(ob + 16 * i + 4 * fg) = pk;
        }
    }
}

// ---------------------------------------------------------------------------
extern "C" void kernel_launch(void* const* d_in, const int* in_sizes, int n_in,
                              void* d_out, int out_size, void* d_ws, size_t ws_size,
                              hipStream_t stream)
{
    const float* x      = (const float*)d_in[0];
    const float* wq     = (const float*)d_in[1];
    const float* wk     = (const float*)d_in[2];
    const float* wv     = (const float*)d_in[3];
    const float* w_proj = (const float*)d_in[4];
    const float* b_proj = (const float*)d_in[5];
    const float* w1     = (const float*)d_in[6];
    const float* b1     = (const float*)d_in[7];
    const float* w2     = (const float*)d_in[8];
    const float* b2     = (const float*)d_in[9];
    const float* ln1_g  = (const float*)d_in[10];
    const float* ln1_b  = (const float*)d_in[11];
    const float* ln2_g  = (const float*)d_in[12];
    const float* ln2_b  = (const float*)d_in[13];
    float* out = (float*)d_out;

    char* w = (char*)d_ws;
    size_t off = 0;
    auto alloc = [&](size_t bytes) {
        void* p = w + off;
        off += (bytes + 255) & ~(size_t)255;
        return p;
    };
    __hip_bfloat16* h_ln    = (__hip_bfloat16*)alloc(8192ull * 768 * 2);
    __hip_bfloat16* wt_qkv  = (__hip_bfloat16*)alloc(2304ull * 768 * 2);
    __hip_bfloat16* wt_proj = (__hip_bfloat16*)alloc(768ull * 768 * 2);
    __hip_bfloat16* wt1     = (__hip_bfloat16*)alloc(3072ull * 768 * 2);
    __hip_bfloat16* wt2     = (__hip_bfloat16*)alloc(768ull * 3072 * 2);
    __hip_bfloat16* qbuf    = (__hip_bfloat16*)alloc(8192ull * 768 * 2);
    __hip_bfloat16* kbuf    = (__hip_bfloat16*)alloc(8192ull * 768 * 2);
    __hip_bfloat16* vbuf    = (__hip_bfloat16*)alloc(8192ull * 768 * 2);
    __hip_bfloat16* attn_o  = (__hip_bfloat16*)alloc(8192ull * 768 * 2);
    float*          x1      = (float*)alloc(8192ull * 768 * 4);
    __hip_bfloat16* h2      = (__hip_bfloat16*)alloc(8192ull * 768 * 2);
    __hip_bfloat16* a1      = qbuf;  // alias: q/k/v/attn_o dead by FFN1

    conv_qkv<<<dim3(24, 2, 36), dim3(32, 8), 0, stream>>>(wq, wk, wv, wt_qkv);
    transpose_w<<<dim3(24, 24), dim3(32, 8), 0, stream>>>(w_proj, wt_proj, 768, 768);
    transpose_w<<<dim3(96, 24), dim3(32, 8), 0, stream>>>(w1, wt1, 768, 3072);
    transpose_w<<<dim3(24, 96), dim3(32, 8), 0, stream>>>(w2, wt2, 3072, 768);

    ln_kernel<<<8192, 256, 0, stream>>>(x, ln1_g, ln1_b, h_ln);
    gemm_kernel<1><<<dim3(18, 64), 256, 0, stream>>>(
        h_ln, wt_qkv, nullptr, nullptr, qbuf, kbuf, vbuf, 8192, 2304, 768);
    attn_kernel<<<dim3(16, 48), 256, 0, stream>>>(qbuf, kbuf, vbuf, attn_o);
    gemm_kernel<2><<<dim3(6, 64), 256, 0, stream>>>(
        attn_o, wt_proj, b_proj, x, x1, nullptr, nullptr, 8192, 768, 768);

    ln_kernel<<<8192, 256, 0, stream>>>(x1, ln2_g, ln2_b, h2);
    gemm_kernel<3><<<dim3(24, 64), 256, 0, stream>>>(
        h2, wt1, b1, nullptr, a1, nullptr, nullptr, 8192, 3072, 768);
    gemm_kernel<2><<<dim3(6, 64), 256, 0, stream>>>(
        a1, wt2, b2, x1, out, nullptr, nullptr, 8192, 768, 3072);
}

// Round 7
// 249.594 us; speedup vs baseline: 1.7012x; 1.0349x over previous
//
#include <hip/hip_runtime.h>
#include <hip/hip_bf16.h>

typedef __attribute__((ext_vector_type(8))) short bf16x8;
typedef __attribute__((ext_vector_type(4))) short bf16x4;
typedef __attribute__((ext_vector_type(4))) float f32x4;

#define AS1 __attribute__((address_space(1)))
#define AS3 __attribute__((address_space(3)))

// ---------------------------------------------------------------- LayerNorm
__global__ __launch_bounds__(256)
void ln_kernel(const float* __restrict__ x, const float* __restrict__ g,
               const float* __restrict__ b, __hip_bfloat16* __restrict__ out)
{
    const int row = blockIdx.x;
    const float* xr = x + (size_t)row * 768;
    const int t = threadIdx.x;
    float v0 = xr[t], v1 = xr[t + 256], v2 = xr[t + 512];
    float s = v0 + v1 + v2;
    float ss = v0 * v0 + v1 * v1 + v2 * v2;
#pragma unroll
    for (int off = 1; off < 64; off <<= 1) {
        s  += __shfl_xor(s, off, 64);
        ss += __shfl_xor(ss, off, 64);
    }
    __shared__ float red[8];
    const int wv = t >> 6;
    if ((t & 63) == 0) { red[wv] = s; red[wv + 4] = ss; }
    __syncthreads();
    s  = red[0] + red[1] + red[2] + red[3];
    ss = red[4] + red[5] + red[6] + red[7];
    const float mu = s * (1.0f / 768.0f);
    const float rstd = rsqrtf(ss * (1.0f / 768.0f) - mu * mu + 1e-5f);
    __hip_bfloat16* orow = out + (size_t)row * 768;
    orow[t]       = __float2bfloat16((v0 - mu) * rstd * g[t]       + b[t]);
    orow[t + 256] = __float2bfloat16((v1 - mu) * rstd * g[t + 256] + b[t + 256]);
    orow[t + 512] = __float2bfloat16((v2 - mu) * rstd * g[t + 512] + b[t + 512]);
}

// ------------------------------------------------- weight transpose f32->bf16
__global__ __launch_bounds__(256)
void transpose_w(const float* __restrict__ in, __hip_bfloat16* __restrict__ out,
                 int R, int C)
{
    __shared__ float tile[32][33];
    const int c0 = blockIdx.x * 32, r0 = blockIdx.y * 32;
    const int tx = threadIdx.x, ty = threadIdx.y;
#pragma unroll
    for (int i = 0; i < 4; i++)
        tile[ty + i * 8][tx] = in[(size_t)(r0 + ty + i * 8) * C + c0 + tx];
    __syncthreads();
#pragma unroll
    for (int i = 0; i < 4; i++)
        out[(size_t)(c0 + ty + i * 8) * R + r0 + tx] =
            __float2bfloat16(tile[tx][ty + i * 8]);
}

// ---------------------------------------------- QKV weight pack: [H,C,D] f32
__global__ __launch_bounds__(256)
void conv_qkv(const float* __restrict__ wq, const float* __restrict__ wk,
              const float* __restrict__ wv, __hip_bfloat16* __restrict__ out)
{
    const int z = blockIdx.z;
    const int mat = z / 12, h = z % 12;
    const float* w = (mat == 0) ? wq : ((mat == 1) ? wk : wv);
    __shared__ float tile[32][33];
    const int c0 = blockIdx.x * 32;
    const int d0 = blockIdx.y * 32;
    const int tx = threadIdx.x, ty = threadIdx.y;
#pragma unroll
    for (int i = 0; i < 4; i++)
        tile[ty + i * 8][tx] =
            w[(size_t)h * 768 * 64 + (size_t)(c0 + ty + i * 8) * 64 + d0 + tx];
    __syncthreads();
#pragma unroll
    for (int i = 0; i < 4; i++)
        out[(size_t)(mat * 768 + h * 64 + d0 + ty + i * 8) * 768 + c0 + tx] =
            __float2bfloat16(tile[tx][ty + i * 8]);
}

// ------------------------------------------------------------------- GEMM
// C[M,N] = A[M,K] (bf16 row-major) * Bt[N,K]^T. BK=64, XOR-swizzled LDS tiles
// (T2), XCD-chunked work remap (T1). Unchanged from R5.
template<int MODE>
__global__ __launch_bounds__(256)
void gemm_kernel(const __hip_bfloat16* __restrict__ A,
                 const __hip_bfloat16* __restrict__ Bt,
                 const float* __restrict__ bias,
                 const float* __restrict__ res,
                 void* __restrict__ outp,
                 __hip_bfloat16* __restrict__ outK,
                 __hip_bfloat16* __restrict__ outV,
                 int M, int N, int K)
{
    __shared__ alignas(16) char As[128 * 128];   // [128 m][64 k] bf16, swizzled
    __shared__ alignas(16) char Bs[128 * 128];   // [128 n][64 k] bf16, swizzled
    const int tid = threadIdx.x;
    const int wave = tid >> 6, lane = tid & 63;

    // T1: XCD-chunked remap of linearized workgroup id
    const int nwgx = gridDim.x;
    const int hw = blockIdx.x + nwgx * blockIdx.y;
    const int nwg = nwgx * gridDim.y;
    const int q8 = nwg >> 3;                    // all grids divisible by 8
    const int work = (hw & 7) * q8 + (hw >> 3);
    const int m0 = (work / nwgx) * 128, n0 = (work % nwgx) * 128;

    const int wm = (wave >> 1) * 64, wn = (wave & 1) * 64;
    f32x4 acc[4][4] = {};

    // staging: chunk n = tid + 256r covers LDS bytes n*16..+16 (linear dest)
    int soff[4];
#pragma unroll
    for (int r = 0; r < 4; r++) {
        const int n = tid + 256 * r;
        const int row = n >> 3;
        soff[r] = row * (K * 2) + ((((n & 7) << 4)) ^ ((row & 7) << 4));
    }

    const int fr = lane & 15, fg = lane >> 4;

    for (int k0 = 0; k0 < K; k0 += 64) {
        __syncthreads();
        const char* ga = (const char*)A  + (size_t)m0 * K * 2 + k0 * 2;
        const char* gb = (const char*)Bt + (size_t)n0 * K * 2 + k0 * 2;
#pragma unroll
        for (int r = 0; r < 4; r++) {
            __builtin_amdgcn_global_load_lds((const AS1 void*)(ga + soff[r]),
                (AS3 void*)(As + r * 4096 + tid * 16), 16, 0, 0);
            __builtin_amdgcn_global_load_lds((const AS1 void*)(gb + soff[r]),
                (AS3 void*)(Bs + r * 4096 + tid * 16), 16, 0, 0);
        }
        __syncthreads();
        bf16x8 af[4][2], bfr[4][2];
#pragma unroll
        for (int i = 0; i < 4; i++)
#pragma unroll
            for (int ks = 0; ks < 2; ks++)
                af[i][ks] = *(const bf16x8*)(As + (wm + i * 16 + fr) * 128 +
                            ((fg * 16 + ks * 64) ^ ((fr & 7) << 4)));
#pragma unroll
        for (int j = 0; j < 4; j++)
#pragma unroll
            for (int ks = 0; ks < 2; ks++)
                bfr[j][ks] = *(const bf16x8*)(Bs + (wn + j * 16 + fr) * 128 +
                             ((fg * 16 + ks * 64) ^ ((fr & 7) << 4)));
        __builtin_amdgcn_s_setprio(1);
#pragma unroll
        for (int ks = 0; ks < 2; ks++)
#pragma unroll
            for (int i = 0; i < 4; i++)
#pragma unroll
                for (int j = 0; j < 4; j++)
                    acc[i][j] = __builtin_amdgcn_mfma_f32_16x16x32_bf16(
                        af[i][ks], bfr[j][ks], acc[i][j], 0, 0, 0);
        __builtin_amdgcn_s_setprio(0);
    }

#pragma unroll
    for (int j = 0; j < 4; j++) {
        const int n = n0 + wn + j * 16 + fr;
        if (MODE == 1 && n >= 1536) {
            // V transposed: vbuf[bh][d][t], vector store along t
            const int hh = (n - 1536) >> 6, dd = (n - 1536) & 63;
#pragma unroll
            for (int i = 0; i < 4; i++) {
                const int m = m0 + wm + i * 16 + fg * 4;
                const int bidx = m >> 11, tt = m & 2047;
                bf16x4 pk;
                __hip_bfloat16* pp = (__hip_bfloat16*)&pk;
#pragma unroll
                for (int r = 0; r < 4; r++)
                    pp[r] = __float2bfloat16(acc[i][j][r]);
                *(bf16x4*)&outV[(((size_t)bidx * 12 + hh) * 64 + dd) * 2048 + tt] = pk;
            }
            continue;
        }
        const float bv = (MODE == 2 || MODE == 3) ? bias[n] : 0.0f;
#pragma unroll
        for (int i = 0; i < 4; i++) {
#pragma unroll
            for (int r = 0; r < 4; r++) {
                const int m = m0 + wm + i * 16 + fg * 4 + r;
                float v = acc[i][j][r] + bv;
                if (MODE == 3) v = fmaxf(v, 0.0f);
                if (MODE == 2) {
                    ((float*)outp)[(size_t)m * N + n] = res[(size_t)m * N + n] + v;
                } else if (MODE == 1) {
                    __hip_bfloat16* dst; int nc;
                    if (n < 768) { dst = (__hip_bfloat16*)outp; nc = n;
                                   v *= 0.18033688011112042f; /* 0.125*log2e */ }
                    else         { dst = outK; nc = n - 768; }
                    const int hh = nc >> 6, dd = nc & 63;
                    const int bidx = m >> 11, tt = m & 2047;
                    dst[(((size_t)bidx * 12 + hh) * 2048 + tt) * 64 + dd] =
                        __float2bfloat16(v);
                } else {
                    ((__hip_bfloat16*)outp)[(size_t)m * N + n] = __float2bfloat16(v);
                }
            }
        }
    }
}

// ----------------------------------------------------------- causal attention
// Work-balanced paired q-tiles + XCD-local head mapping (R6), plus SHUFFLE-FREE
// steady state: denominator accumulated via an extra ones-fragment PV MFMA
// (matrix unit computes the P column-sums; rescale applies automatically), and
// the defer-max test uses per-lane partial maxima with __all — the cross-lane
// max shuffles run only inside the rare rescale branch.
__global__ __launch_bounds__(256)
void attn_kernel(const __hip_bfloat16* __restrict__ Q,
                 const __hip_bfloat16* __restrict__ Kg,
                 const __hip_bfloat16* __restrict__ Vg,
                 __hip_bfloat16* __restrict__ out)
{
    __shared__ alignas(16) char lds[32768];   // [cur][ K 8KB | V^T 8KB ]
    const int tid = threadIdx.x, wave = tid >> 6, lane = tid & 63;
    const int fr = lane & 15, fg = lane >> 4;

    // XCD-local head mapping: grid is (16, 48), hw = bx' + 16*bh'.
    const int hw = blockIdx.x + 16 * blockIdx.y;
    const int xcd = hw & 7, chunk = hw >> 3;      // 96 chunks per XCD
    const int bh = xcd * 6 + (chunk >> 4);        // 6 heads per XCD
    const int bx = chunk & 15;                    // 16 q-blocks per head

    const int b = bh / 12, h = bh % 12;
    const __hip_bfloat16* qb = Q  + (size_t)bh * 2048 * 64;
    const __hip_bfloat16* kb = Kg + (size_t)bh * 2048 * 64;
    const __hip_bfloat16* vb = Vg + (size_t)bh * 2048 * 64;   // [64 d][2048 t]

    int ksoff[2], vsoff[2];
#pragma unroll
    for (int r = 0; r < 2; r++) {
        const int n = wave * 64 + lane + 256 * r;
        const int row = n >> 3;
        const int swz = (((n & 7) << 4)) ^ ((row & 7) << 4);
        ksoff[r] = row * 128  + swz;
        vsoff[r] = row * 4096 + swz;
    }

    auto STAGE = [&](int cur, int kv0) {
        const char* kx = (const char*)kb + (size_t)kv0 * 128;
        const char* vx = (const char*)vb + (size_t)kv0 * 2;
#pragma unroll
        for (int r = 0; r < 2; r++) {
            __builtin_amdgcn_global_load_lds((const AS1 void*)(kx + ksoff[r]),
                (AS3 void*)(lds + cur * 16384 + r * 4096 + wave * 1024), 16, 0, 0);
            __builtin_amdgcn_global_load_lds((const AS1 void*)(vx + vsoff[r]),
                (AS3 void*)(lds + cur * 16384 + 8192 + r * 4096 + wave * 1024), 16, 0, 0);
        }
    };

    const bf16x4 ones = {(short)0x3F80, (short)0x3F80,
                         (short)0x3F80, (short)0x3F80};   // bf16 1.0 x4

#pragma unroll
    for (int pass = 0; pass < 2; ++pass) {
        const int g = pass ? (31 - bx) : bx;
        const int q0w = g * 64 + wave * 16;
        const int qv = q0w + fr;

        bf16x8 qf0 = *(const bf16x8*)(qb + (size_t)qv * 64 + fg * 8);
        bf16x8 qf1 = *(const bf16x8*)(qb + (size_t)qv * 64 + 32 + fg * 8);

        f32x4 o[4] = {};
        f32x4 o_l = {};                 // running denominator (all rows equal)
        float mrun = -1e30f;
        const int NT = g + 1;

        STAGE(0, 0);
        __syncthreads();
        int cur = 0;

        for (int t = 0; t < NT; ++t) {
            if (t + 1 < NT) STAGE(cur ^ 1, (t + 1) << 6);
            const int kv0 = t << 6;
            const char* Kb = lds + cur * 16384;
            const char* Vb = Kb + 8192;
            bf16x8 kf[4][2];
#pragma unroll
            for (int c = 0; c < 4; c++)
#pragma unroll
                for (int hh = 0; hh < 2; hh++)
                    kf[c][hh] = *(const bf16x8*)(Kb + (16 * c + fr) * 128 +
                                ((hh * 64 + fg * 16) ^ ((fr & 7) << 4)));
            f32x4 s[4];
            __builtin_amdgcn_s_setprio(1);
#pragma unroll
            for (int c = 0; c < 4; c++) {
                f32x4 z = {};
                s[c] = __builtin_amdgcn_mfma_f32_16x16x32_bf16(
                    kf[c][0], qf0, z, 0, 0, 0);
                s[c] = __builtin_amdgcn_mfma_f32_16x16x32_bf16(
                    kf[c][1], qf1, s[c], 0, 0, 0);
            }
            __builtin_amdgcn_s_setprio(0);
            if (t == NT - 1) {
#pragma unroll
                for (int c = 0; c < 4; c++)
#pragma unroll
                    for (int r = 0; r < 4; r++)
                        if (kv0 + 16 * c + 4 * fg + r > qv) s[c][r] = -1e30f;
            }
            // per-lane partial max (balanced tree); shuffles only if rescale
            float t0 = fmaxf(fmaxf(s[0][0], s[0][1]), fmaxf(s[0][2], s[0][3]));
            float t1 = fmaxf(fmaxf(s[1][0], s[1][1]), fmaxf(s[1][2], s[1][3]));
            float t2 = fmaxf(fmaxf(s[2][0], s[2][1]), fmaxf(s[2][2], s[2][3]));
            float t3 = fmaxf(fmaxf(s[3][0], s[3][1]), fmaxf(s[3][2], s[3][3]));
            const float tm = fmaxf(fmaxf(t0, t1), fmaxf(t2, t3));
            if (!__all(tm <= mrun + 8.f)) {      // defer-max (T13)
                float tf = fmaxf(tm, __shfl_xor(tm, 16, 64));
                tf = fmaxf(tf, __shfl_xor(tf, 32, 64));
                const float mnew = fmaxf(mrun, tf);
                const float al = exp2f(mrun - mnew);
#pragma unroll
                for (int i = 0; i < 4; i++)
#pragma unroll
                    for (int e = 0; e < 4; e++) o[i][e] *= al;
#pragma unroll
                for (int e = 0; e < 4; e++) o_l[e] *= al;
                mrun = mnew;
            }
            bf16x4 pf[4];
#pragma unroll
            for (int c = 0; c < 4; c++) {
                const float p0 = exp2f(s[c][0] - mrun), p1 = exp2f(s[c][1] - mrun);
                const float p2 = exp2f(s[c][2] - mrun), p3 = exp2f(s[c][3] - mrun);
                __hip_bfloat16* pp = (__hip_bfloat16*)&pf[c];
                pp[0] = __float2bfloat16(p0); pp[1] = __float2bfloat16(p1);
                pp[2] = __float2bfloat16(p2); pp[3] = __float2bfloat16(p3);
            }
            bf16x4 vf[4][4];
#pragma unroll
            for (int i = 0; i < 4; i++)
#pragma unroll
                for (int c = 0; c < 4; c++)
                    vf[i][c] = *(const bf16x4*)(Vb + (16 * i + fr) * 128 +
                                ((32 * c + 8 * fg) ^ ((fr & 7) << 4)));
            __builtin_amdgcn_s_setprio(1);
#pragma unroll
            for (int c = 0; c < 4; c++)          // denominator: P column-sums
                o_l = __builtin_amdgcn_mfma_f32_16x16x16bf16_1k(
                    ones, pf[c], o_l, 0, 0, 0);
#pragma unroll
            for (int i = 0; i < 4; i++)
#pragma unroll
                for (int c = 0; c < 4; c++)
                    o[i] = __builtin_amdgcn_mfma_f32_16x16x16bf16_1k(
                        vf[i][c], pf[c], o[i], 0, 0, 0);
            __builtin_amdgcn_s_setprio(0);
            __syncthreads();
            cur ^= 1;
        }

        const float inv = 1.0f / o_l[0];
        __hip_bfloat16* ob = out + ((size_t)(b * 2048 + qv)) * 768 + h * 64;
#pragma unroll
        for (int i = 0; i < 4; i++) {
            bf16x4 pk;
            __hip_bfloat16* pp = (__hip_bfloat16*)&pk;
#pragma unroll
            for (int r = 0; r < 4; r++)
                pp[r] = __float2bfloat16(o[i][r] * inv);
            *(bf16x4*)(ob + 16 * i + 4 * fg) = pk;
        }
    }
}

// ---------------------------------------------------------------------------
extern "C" void kernel_launch(void* const* d_in, const int* in_sizes, int n_in,
                              void* d_out, int out_size, void* d_ws, size_t ws_size,
                              hipStream_t stream)
{
    const float* x      = (const float*)d_in[0];
    const float* wq     = (const float*)d_in[1];
    const float* wk     = (const float*)d_in[2];
    const float* wv     = (const float*)d_in[3];
    const float* w_proj = (const float*)d_in[4];
    const float* b_proj = (const float*)d_in[5];
    const float* w1     = (const float*)d_in[6];
    const float* b1     = (const float*)d_in[7];
    const float* w2     = (const float*)d_in[8];
    const float* b2     = (const float*)d_in[9];
    const float* ln1_g  = (const float*)d_in[10];
    const float* ln1_b  = (const float*)d_in[11];
    const float* ln2_g  = (const float*)d_in[12];
    const float* ln2_b  = (const float*)d_in[13];
    float* out = (float*)d_out;

    char* w = (char*)d_ws;
    size_t off = 0;
    auto alloc = [&](size_t bytes) {
        void* p = w + off;
        off += (bytes + 255) & ~(size_t)255;
        return p;
    };
    __hip_bfloat16* h_ln    = (__hip_bfloat16*)alloc(8192ull * 768 * 2);
    __hip_bfloat16* wt_qkv  = (__hip_bfloat16*)alloc(2304ull * 768 * 2);
    __hip_bfloat16* wt_proj = (__hip_bfloat16*)alloc(768ull * 768 * 2);
    __hip_bfloat16* wt1     = (__hip_bfloat16*)alloc(3072ull * 768 * 2);
    __hip_bfloat16* wt2     = (__hip_bfloat16*)alloc(768ull * 3072 * 2);
    __hip_bfloat16* qbuf    = (__hip_bfloat16*)alloc(8192ull * 768 * 2);
    __hip_bfloat16* kbuf    = (__hip_bfloat16*)alloc(8192ull * 768 * 2);
    __hip_bfloat16* vbuf    = (__hip_bfloat16*)alloc(8192ull * 768 * 2);
    __hip_bfloat16* attn_o  = (__hip_bfloat16*)alloc(8192ull * 768 * 2);
    float*          x1      = (float*)alloc(8192ull * 768 * 4);
    __hip_bfloat16* h2      = (__hip_bfloat16*)alloc(8192ull * 768 * 2);
    __hip_bfloat16* a1      = qbuf;  // alias: q/k/v/attn_o dead by FFN1

    conv_qkv<<<dim3(24, 2, 36), dim3(32, 8), 0, stream>>>(wq, wk, wv, wt_qkv);
    transpose_w<<<dim3(24, 24), dim3(32, 8), 0, stream>>>(w_proj, wt_proj, 768, 768);
    transpose_w<<<dim3(96, 24), dim3(32, 8), 0, stream>>>(w1, wt1, 768, 3072);
    transpose_w<<<dim3(24, 96), dim3(32, 8), 0, stream>>>(w2, wt2, 3072, 768);

    ln_kernel<<<8192, 256, 0, stream>>>(x, ln1_g, ln1_b, h_ln);
    gemm_kernel<1><<<dim3(18, 64), 256, 0, stream>>>(
        h_ln, wt_qkv, nullptr, nullptr, qbuf, kbuf, vbuf, 8192, 2304, 768);
    attn_kernel<<<dim3(16, 48), 256, 0, stream>>>(qbuf, kbuf, vbuf, attn_o);
    gemm_kernel<2><<<dim3(6, 64), 256, 0, stream>>>(
        attn_o, wt_proj, b_proj, x, x1, nullptr, nullptr, 8192, 768, 768);

    ln_kernel<<<8192, 256, 0, stream>>>(x1, ln2_g, ln2_b, h2);
    gemm_kernel<3><<<dim3(24, 64), 256, 0, stream>>>(
        h2, wt1, b1, nullptr, a1, nullptr, nullptr, 8192, 3072, 768);
    gemm_kernel<2><<<dim3(6, 64), 256, 0, stream>>>(
        a1, wt2, b2, x1, out, nullptr, nullptr, 8192, 768, 3072);
}